// Round 3
// baseline (830.974 us; speedup 1.0000x reference)
//
#include <hip/hip_runtime.h>
#include <hip/hip_bf16.h>

typedef __bf16 bf16;
typedef __bf16 bf16x8 __attribute__((ext_vector_type(8)));
typedef float  floatx4 __attribute__((ext_vector_type(4)));

#define D_MODEL   1024
#define NUM_HEADS 16
#define NUM_GROUPS 4
#define DK        64
#define SEQ_T     2048
#define BATCH     2
#define M_ROWS    (BATCH*SEQ_T)   // 4096
#define WINDOW    512

// ---------------------------------------------------------------------------
// Runtime input-dtype probe. For packed-bf16 buffers, bits 14..7 of a 32-bit
// word are the low element's exponent (~[119,129] for N(0,1) data). For fp32
// buffers they are mantissa bits (uniform). flag=1 -> bf16, flag=0 -> fp32.
// ---------------------------------------------------------------------------
__global__ void detect_dtype(const unsigned* __restrict__ x, int* __restrict__ flag)
{
    __shared__ int cnt;
    if (threadIdx.x == 0) cnt = 0;
    __syncthreads();
    int local = 0;
    for (int i = threadIdx.x; i < 1024; i += 256) {
        unsigned e = (x[i] >> 7) & 0xFFu;
        local += (e >= 100u && e <= 140u) ? 1 : 0;
    }
    atomicAdd(&cnt, local);
    __syncthreads();
    if (threadIdx.x == 0) flag[0] = (cnt > 512) ? 1 : 0;
}

// ---------------------------------------------------------------------------
// GEMM: C[M,N] = A[M,K] @ W[N,K]^T. LDS tiles always bf16; external buffers
// (aext/wext/cext) are read/written as fp32 when flag==0, bf16 when flag==1.
// 128x128 tile, 4 waves 2x2, 16x16x32 MFMA (verified m92 fragment layouts).
// ---------------------------------------------------------------------------
__global__ __launch_bounds__(256)
void gemm_bt(const void* __restrict__ Av, const void* __restrict__ Wv,
             void* __restrict__ Cv, int M, int N, int K,
             const int* __restrict__ flag, int aext, int wext, int cext)
{
    const bool f32in = (flag[0] == 0);
    const bool a32 = aext && f32in;
    const bool w32 = wext && f32in;
    const bool c32 = cext && f32in;

    const int SA = 40;
    __shared__ bf16 As[128 * SA];
    __shared__ bf16 Bs[128 * SA];

    const int tid  = threadIdx.x;
    const int wave = tid >> 6;
    const int lane = tid & 63;
    const int m0 = blockIdx.y * 128;
    const int n0 = blockIdx.x * 128;
    const int wm = (wave >> 1) * 64;
    const int wn = (wave & 1) * 64;
    const int lr   = lane & 15;
    const int quad = lane >> 4;

    floatx4 acc[4][4];
#pragma unroll
    for (int i = 0; i < 4; i++)
#pragma unroll
        for (int j = 0; j < 4; j++) acc[i][j] = (floatx4)(0.0f);

    for (int k0 = 0; k0 < K; k0 += 32) {
#pragma unroll
        for (int i = 0; i < 2; i++) {
            int c    = tid + i * 256;
            int row  = c >> 2;
            int col8 = (c & 3) * 8;
            size_t goff = (size_t)(m0 + row) * K + k0 + col8;
            if (!a32) {
                *(bf16x8*)&As[row * SA + col8] = *(const bf16x8*)((const bf16*)Av + goff);
            } else {
                const float* Af = (const float*)Av + goff;
                float4 f0 = *(const float4*)Af;
                float4 f1 = *(const float4*)(Af + 4);
                bf16x8 v;
                v[0] = (bf16)f0.x; v[1] = (bf16)f0.y; v[2] = (bf16)f0.z; v[3] = (bf16)f0.w;
                v[4] = (bf16)f1.x; v[5] = (bf16)f1.y; v[6] = (bf16)f1.z; v[7] = (bf16)f1.w;
                *(bf16x8*)&As[row * SA + col8] = v;
            }
            size_t woff = (size_t)(n0 + row) * K + k0 + col8;
            if (!w32) {
                *(bf16x8*)&Bs[row * SA + col8] = *(const bf16x8*)((const bf16*)Wv + woff);
            } else {
                const float* Wf = (const float*)Wv + woff;
                float4 f0 = *(const float4*)Wf;
                float4 f1 = *(const float4*)(Wf + 4);
                bf16x8 v;
                v[0] = (bf16)f0.x; v[1] = (bf16)f0.y; v[2] = (bf16)f0.z; v[3] = (bf16)f0.w;
                v[4] = (bf16)f1.x; v[5] = (bf16)f1.y; v[6] = (bf16)f1.z; v[7] = (bf16)f1.w;
                *(bf16x8*)&Bs[row * SA + col8] = v;
            }
        }
        __syncthreads();

        bf16x8 afr[4], bfr[4];
#pragma unroll
        for (int mi = 0; mi < 4; mi++)
            afr[mi] = *(const bf16x8*)&As[(wm + mi * 16 + lr) * SA + quad * 8];
#pragma unroll
        for (int ni = 0; ni < 4; ni++)
            bfr[ni] = *(const bf16x8*)&Bs[(wn + ni * 16 + lr) * SA + quad * 8];

#pragma unroll
        for (int mi = 0; mi < 4; mi++)
#pragma unroll
            for (int ni = 0; ni < 4; ni++)
                acc[mi][ni] = __builtin_amdgcn_mfma_f32_16x16x32_bf16(
                    afr[mi], bfr[ni], acc[mi][ni], 0, 0, 0);
        __syncthreads();
    }

#pragma unroll
    for (int mi = 0; mi < 4; mi++) {
#pragma unroll
        for (int ni = 0; ni < 4; ni++) {
#pragma unroll
            for (int r = 0; r < 4; r++) {
                int row = m0 + wm + mi * 16 + quad * 4 + r;
                int col = n0 + wn + ni * 16 + lr;
                float val = acc[mi][ni][r];
                if (c32) ((float*)Cv)[(size_t)row * N + col] = val;
                else     ((bf16*)Cv)[(size_t)row * N + col] = (bf16)val;
            }
        }
    }
}

// ---------------------------------------------------------------------------
// RoPE, interleaved pairs, in-place on bf16 workspace [rows, heads*64].
// ---------------------------------------------------------------------------
__global__ __launch_bounds__(256)
void rope_kernel(bf16* __restrict__ X, const int* __restrict__ pos,
                 int rows, int heads)
{
    int idx = blockIdx.x * 256 + threadIdx.x;
    int total = rows * heads * 32;
    if (idx >= total) return;
    int i   = idx & 31;
    int h   = (idx >> 5) % heads;
    int row = idx / (heads * 32);
    int t   = row & (SEQ_T - 1);
    float p   = (float)pos[t];
    float inv = exp2f(-(float)i * (13.287712379549449f / 32.0f));
    float ang = p * inv;
    float c = cosf(ang), s = sinf(ang);
    size_t base = (size_t)row * heads * 64 + (size_t)h * 64 + 2 * i;
    float x1 = (float)X[base], x2 = (float)X[base + 1];
    X[base]     = (bf16)(x1 * c - x2 * s);
    X[base + 1] = (bf16)(x1 * s + x2 * c);
}

// ---------------------------------------------------------------------------
// Windowed causal attention, online softmax, fp32 math, bf16 workspace I/O.
// ---------------------------------------------------------------------------
__global__ __launch_bounds__(256)
void attn_kernel(const bf16* __restrict__ Q, const bf16* __restrict__ K,
                 const bf16* __restrict__ V, bf16* __restrict__ AO)
{
    const int TQ = 32, TK = 64, ST = 65;
    __shared__ float qs[TQ * ST];
    __shared__ float ks[TK * ST];
    __shared__ float vs[TK * ST];
    __shared__ float ps[TQ * ST];

    const int tid = threadIdx.x;
    const int qt = blockIdx.x, bh = blockIdx.y;
    const int b = bh >> 4, h = bh & 15, g = h >> 2;
    const int q0 = qt * TQ;
    const int qi = tid >> 3, oct = tid & 7;

    {
        int c = tid;
        int row = c >> 3, col8 = (c & 7) * 8;
        bf16x8 v8 = *(const bf16x8*)&Q[((size_t)(b * SEQ_T + q0 + row)) * D_MODEL + h * 64 + col8];
#pragma unroll
        for (int j = 0; j < 8; j++) qs[row * ST + col8 + j] = (float)v8[j];
    }

    float m = -1e30f, l = 0.0f;
    float o[8];
#pragma unroll
    for (int d = 0; d < 8; d++) o[d] = 0.0f;

    const int i_abs = q0 + qi;
    const int j_lo = (q0 >= WINDOW) ? ((q0 - WINDOW) & ~63) : 0;
    const int j_hi = q0 + TQ - 1;

    for (int j0 = j_lo; j0 <= j_hi; j0 += TK) {
        __syncthreads();
#pragma unroll
        for (int i = 0; i < 2; i++) {
            int c = tid + i * 256;
            int row = c >> 3, col8 = (c & 7) * 8;
            int krow = j0 + row; if (krow > SEQ_T - 1) krow = SEQ_T - 1;  // clamp (masked anyway)
            size_t gro = ((size_t)(b * SEQ_T + krow)) * (NUM_GROUPS * DK) + g * 64 + col8;
            bf16x8 kv = *(const bf16x8*)&K[gro];
            bf16x8 vv = *(const bf16x8*)&V[gro];
#pragma unroll
            for (int j = 0; j < 8; j++) {
                ks[row * ST + col8 + j] = (float)kv[j];
                vs[row * ST + col8 + j] = (float)vv[j];
            }
        }
        __syncthreads();

        float s[8];
#pragma unroll
        for (int kk = 0; kk < 8; kk++) s[kk] = 0.0f;
        for (int d = 0; d < 64; d += 4) {
            float qv0 = qs[qi * ST + d + 0];
            float qv1 = qs[qi * ST + d + 1];
            float qv2 = qs[qi * ST + d + 2];
            float qv3 = qs[qi * ST + d + 3];
#pragma unroll
            for (int kk = 0; kk < 8; kk++) {
                int kr = (oct * 8 + kk) * ST + d;
                s[kk] += qv0 * ks[kr] + qv1 * ks[kr + 1] + qv2 * ks[kr + 2] + qv3 * ks[kr + 3];
            }
        }
        float mt = -1e30f;
#pragma unroll
        for (int kk = 0; kk < 8; kk++) {
            int j = j0 + oct * 8 + kk;
            bool valid = (j <= i_abs) && (i_abs - j <= WINDOW);
            s[kk] = valid ? s[kk] * 0.125f : -1e30f;
            mt = fmaxf(mt, s[kk]);
        }
        mt = fmaxf(mt, __shfl_xor(mt, 1));
        mt = fmaxf(mt, __shfl_xor(mt, 2));
        mt = fmaxf(mt, __shfl_xor(mt, 4));
        float m_new = fmaxf(m, mt);
        float ls = 0.0f;
#pragma unroll
        for (int kk = 0; kk < 8; kk++) {
            float p = (s[kk] > -1e29f) ? expf(s[kk] - m_new) : 0.0f;
            ps[qi * ST + oct * 8 + kk] = p;
            ls += p;
        }
        ls += __shfl_xor(ls, 1);
        ls += __shfl_xor(ls, 2);
        ls += __shfl_xor(ls, 4);
        float alpha = expf(m - m_new);
        m = m_new;
        l = l * alpha + ls;
#pragma unroll
        for (int dd = 0; dd < 8; dd++) o[dd] *= alpha;
        __syncthreads();

        for (int kk = 0; kk < 64; kk++) {
            float p = ps[qi * ST + kk];
#pragma unroll
            for (int dd = 0; dd < 8; dd++)
                o[dd] += p * vs[kk * ST + oct * 8 + dd];
        }
    }

    float inv_l = 1.0f / l;
    size_t ob = ((size_t)(b * SEQ_T + q0 + qi)) * D_MODEL + h * 64 + oct * 8;
#pragma unroll
    for (int dd = 0; dd < 8; dd++)
        AO[ob + dd] = (bf16)(o[dd] * inv_l);
}

// ---------------------------------------------------------------------------
extern "C" void kernel_launch(void* const* d_in, const int* in_sizes, int n_in,
                              void* d_out, int out_size, void* d_ws, size_t ws_size,
                              hipStream_t stream)
{
    const void* x  = d_in[0];
    const void* WQ = d_in[1];
    const void* WK = d_in[2];
    const void* WV = d_in[3];
    const void* WO = d_in[4];
    const int* pos = (const int*)d_in[5];

    int*  flag = (int*)d_ws;
    char* ws   = (char*)d_ws + 256;
    bf16* Qw = (bf16*)ws;                                     //  8 MB [4096,1024]
    bf16* Kw = (bf16*)(ws + (size_t) 8 * 1024 * 1024);        //  2 MB [4096,256]
    bf16* Vw = (bf16*)(ws + (size_t)10 * 1024 * 1024);        //  2 MB [4096,256]
    bf16* AO = (bf16*)(ws + (size_t)12 * 1024 * 1024);        //  8 MB [4096,1024]

    detect_dtype<<<1, 256, 0, stream>>>((const unsigned*)x, flag);

    gemm_bt<<<dim3(D_MODEL / 128, M_ROWS / 128), 256, 0, stream>>>(
        x, WQ, Qw, M_ROWS, D_MODEL, D_MODEL, flag, 1, 1, 0);
    gemm_bt<<<dim3((NUM_GROUPS * DK) / 128, M_ROWS / 128), 256, 0, stream>>>(
        x, WK, Kw, M_ROWS, NUM_GROUPS * DK, D_MODEL, flag, 1, 1, 0);
    gemm_bt<<<dim3((NUM_GROUPS * DK) / 128, M_ROWS / 128), 256, 0, stream>>>(
        x, WV, Vw, M_ROWS, NUM_GROUPS * DK, D_MODEL, flag, 1, 1, 0);

    rope_kernel<<<(M_ROWS * NUM_HEADS * 32) / 256, 256, 0, stream>>>(
        Qw, pos, M_ROWS, NUM_HEADS);
    rope_kernel<<<(M_ROWS * NUM_GROUPS * 32) / 256, 256, 0, stream>>>(
        Kw, pos, M_ROWS, NUM_GROUPS);

    attn_kernel<<<dim3(SEQ_T / 32, BATCH * NUM_HEADS), 256, 0, stream>>>(
        Qw, Kw, Vw, AO);

    gemm_bt<<<dim3(D_MODEL / 128, M_ROWS / 128), 256, 0, stream>>>(
        AO, WO, d_out, M_ROWS, D_MODEL, D_MODEL, flag, 0, 1, 1);
}

// Round 4
// 359.939 us; speedup vs baseline: 2.3087x; 2.3087x over previous
//
#include <hip/hip_runtime.h>
#include <hip/hip_bf16.h>

typedef __bf16 bf16;
typedef __bf16 bf16x2 __attribute__((ext_vector_type(2)));
typedef __bf16 bf16x8 __attribute__((ext_vector_type(8)));
typedef float  floatx4 __attribute__((ext_vector_type(4)));

#define D_MODEL   1024
#define NUM_HEADS 16
#define NUM_GROUPS 4
#define DK        64
#define SEQ_T     2048
#define BATCH     2
#define M_ROWS    (BATCH*SEQ_T)   // 4096
#define WINDOW    512
#define KV_DIM    (NUM_GROUPS*DK) // 256

// ---------------------------------------------------------------------------
// Runtime input-dtype probe (kept from R3: inputs proved fp32, but keep robust).
// ---------------------------------------------------------------------------
__global__ void detect_dtype(const unsigned* __restrict__ x, int* __restrict__ flag)
{
    __shared__ int cnt;
    if (threadIdx.x == 0) cnt = 0;
    __syncthreads();
    int local = 0;
    for (int i = threadIdx.x; i < 1024; i += 256) {
        unsigned e = (x[i] >> 7) & 0xFFu;
        local += (e >= 100u && e <= 140u) ? 1 : 0;
    }
    atomicAdd(&cnt, local);
    __syncthreads();
    if (threadIdx.x == 0) flag[0] = (cnt > 512) ? 1 : 0;
}

// ---------------------------------------------------------------------------
// GEMM: C[M,N] = A[M,K] @ W[N,K]^T (unchanged from R3, dtype-flex externals).
// ---------------------------------------------------------------------------
__global__ __launch_bounds__(256)
void gemm_bt(const void* __restrict__ Av, const void* __restrict__ Wv,
             void* __restrict__ Cv, int M, int N, int K,
             const int* __restrict__ flag, int aext, int wext, int cext)
{
    const bool f32in = (flag[0] == 0);
    const bool a32 = aext && f32in;
    const bool w32 = wext && f32in;
    const bool c32 = cext && f32in;

    const int SA = 40;
    __shared__ bf16 As[128 * SA];
    __shared__ bf16 Bs[128 * SA];

    const int tid  = threadIdx.x;
    const int wave = tid >> 6;
    const int lane = tid & 63;
    const int m0 = blockIdx.y * 128;
    const int n0 = blockIdx.x * 128;
    const int wm = (wave >> 1) * 64;
    const int wn = (wave & 1) * 64;
    const int lr   = lane & 15;
    const int quad = lane >> 4;

    floatx4 acc[4][4];
#pragma unroll
    for (int i = 0; i < 4; i++)
#pragma unroll
        for (int j = 0; j < 4; j++) acc[i][j] = (floatx4)(0.0f);

    for (int k0 = 0; k0 < K; k0 += 32) {
#pragma unroll
        for (int i = 0; i < 2; i++) {
            int c    = tid + i * 256;
            int row  = c >> 2;
            int col8 = (c & 3) * 8;
            size_t goff = (size_t)(m0 + row) * K + k0 + col8;
            if (!a32) {
                *(bf16x8*)&As[row * SA + col8] = *(const bf16x8*)((const bf16*)Av + goff);
            } else {
                const float* Af = (const float*)Av + goff;
                float4 f0 = *(const float4*)Af;
                float4 f1 = *(const float4*)(Af + 4);
                bf16x8 v;
                v[0] = (bf16)f0.x; v[1] = (bf16)f0.y; v[2] = (bf16)f0.z; v[3] = (bf16)f0.w;
                v[4] = (bf16)f1.x; v[5] = (bf16)f1.y; v[6] = (bf16)f1.z; v[7] = (bf16)f1.w;
                *(bf16x8*)&As[row * SA + col8] = v;
            }
            size_t woff = (size_t)(n0 + row) * K + k0 + col8;
            if (!w32) {
                *(bf16x8*)&Bs[row * SA + col8] = *(const bf16x8*)((const bf16*)Wv + woff);
            } else {
                const float* Wf = (const float*)Wv + woff;
                float4 f0 = *(const float4*)Wf;
                float4 f1 = *(const float4*)(Wf + 4);
                bf16x8 v;
                v[0] = (bf16)f0.x; v[1] = (bf16)f0.y; v[2] = (bf16)f0.z; v[3] = (bf16)f0.w;
                v[4] = (bf16)f1.x; v[5] = (bf16)f1.y; v[6] = (bf16)f1.z; v[7] = (bf16)f1.w;
                *(bf16x8*)&Bs[row * SA + col8] = v;
            }
        }
        __syncthreads();

        bf16x8 afr[4], bfr[4];
#pragma unroll
        for (int mi = 0; mi < 4; mi++)
            afr[mi] = *(const bf16x8*)&As[(wm + mi * 16 + lr) * SA + quad * 8];
#pragma unroll
        for (int ni = 0; ni < 4; ni++)
            bfr[ni] = *(const bf16x8*)&Bs[(wn + ni * 16 + lr) * SA + quad * 8];

#pragma unroll
        for (int mi = 0; mi < 4; mi++)
#pragma unroll
            for (int ni = 0; ni < 4; ni++)
                acc[mi][ni] = __builtin_amdgcn_mfma_f32_16x16x32_bf16(
                    afr[mi], bfr[ni], acc[mi][ni], 0, 0, 0);
        __syncthreads();
    }

#pragma unroll
    for (int mi = 0; mi < 4; mi++) {
#pragma unroll
        for (int ni = 0; ni < 4; ni++) {
#pragma unroll
            for (int r = 0; r < 4; r++) {
                int row = m0 + wm + mi * 16 + quad * 4 + r;
                int col = n0 + wn + ni * 16 + lr;
                float val = acc[mi][ni][r];
                if (c32) ((float*)Cv)[(size_t)row * N + col] = val;
                else     ((bf16*)Cv)[(size_t)row * N + col] = (bf16)val;
            }
        }
    }
}

// ---------------------------------------------------------------------------
// RoPE, interleaved pairs, in-place on bf16 workspace (unchanged).
// ---------------------------------------------------------------------------
__global__ __launch_bounds__(256)
void rope_kernel(bf16* __restrict__ X, const int* __restrict__ pos,
                 int rows, int heads)
{
    int idx = blockIdx.x * 256 + threadIdx.x;
    int total = rows * heads * 32;
    if (idx >= total) return;
    int i   = idx & 31;
    int h   = (idx >> 5) % heads;
    int row = idx / (heads * 32);
    int t   = row & (SEQ_T - 1);
    float p   = (float)pos[t];
    float inv = exp2f(-(float)i * (13.287712379549449f / 32.0f));
    float ang = p * inv;
    float c = cosf(ang), s = sinf(ang);
    size_t base = (size_t)row * heads * 64 + (size_t)h * 64 + 2 * i;
    float x1 = (float)X[base], x2 = (float)X[base + 1];
    X[base]     = (bf16)(x1 * c - x2 * s);
    X[base + 1] = (bf16)(x1 * s + x2 * c);
}

// ---------------------------------------------------------------------------
// MFMA flash attention: block = 64-query tile for one (b,h); 4 waves, each a
// 16-query stripe. Per 64-key tile: S = QK^T via 16x16x32 MFMA (8/wave),
// online softmax in C-layout regs (row reduce = shfl_xor over quad group),
// P -> LDS (C-layout -> A-frag layout), PV via MFMA against V^T in LDS.
// LDS 39.9 KB -> 4 blocks/CU.
// ---------------------------------------------------------------------------
__global__ __launch_bounds__(256)
void attn_mfma(const bf16* __restrict__ Q, const bf16* __restrict__ K,
               const bf16* __restrict__ V, bf16* __restrict__ AO)
{
    const int ST = 80, STV = 72;   // bf16 elems/row: 160 B and 144 B rows
    __shared__ bf16 Qs[64 * ST];
    __shared__ bf16 Ks[64 * ST];
    __shared__ bf16 Ps[64 * ST];
    __shared__ bf16 Vt[64 * STV];  // Vt[d][k]

    const int tid  = threadIdx.x;
    const int wave = tid >> 6;
    const int lane = tid & 63;
    const int lr   = lane & 15;
    const int quad = lane >> 4;
    const int qt = blockIdx.x, bh = blockIdx.y;
    const int b = bh >> 4, h = bh & 15, g = h >> 2;
    const int q0 = qt * 64;
    const int wq = wave * 16;      // wave's query offset within tile

    // ---- stage Q tile (64x64 bf16) ----
#pragma unroll
    for (int i = 0; i < 2; i++) {
        int c = tid + i * 256;
        int row = c >> 3, col8 = (c & 7) * 8;
        *(bf16x8*)&Qs[row * ST + col8] =
            *(const bf16x8*)&Q[((size_t)(b * SEQ_T + q0 + row)) * D_MODEL + h * 64 + col8];
    }
    __syncthreads();

    bf16x8 qf[2];
#pragma unroll
    for (int ks = 0; ks < 2; ks++)
        qf[ks] = *(const bf16x8*)&Qs[(wq + lr) * ST + ks * 32 + quad * 8];

    float mrow[4], lsum[4];
    floatx4 o[4];
#pragma unroll
    for (int r = 0; r < 4; r++) { mrow[r] = -1e30f; lsum[r] = 0.0f; }
#pragma unroll
    for (int nt = 0; nt < 4; nt++) o[nt] = (floatx4)(0.0f);

    const int t0 = (q0 >= WINDOW) ? (q0 - WINDOW) : 0;

    for (int j0 = t0; j0 <= q0; j0 += 64) {
        __syncthreads();   // protect Ks/Vt from previous-iter readers
        // ---- stage K tile (rows coalesced) ----
#pragma unroll
        for (int i = 0; i < 2; i++) {
            int c = tid + i * 256;
            int row = c >> 3, col8 = (c & 7) * 8;
            *(bf16x8*)&Ks[row * ST + col8] =
                *(const bf16x8*)&K[((size_t)(b * SEQ_T + j0 + row)) * KV_DIM + g * 64 + col8];
        }
        // ---- stage V transposed: Vt[d][k]; coalesced reads, paired writes ----
        {
            int d = tid & 63, kp = tid >> 6;   // kp in 0..3, keys kp*16 + 2j (+1)
#pragma unroll
            for (int j = 0; j < 8; j++) {
                int k = kp * 16 + 2 * j;
                size_t gb = ((size_t)(b * SEQ_T + j0 + k)) * KV_DIM + g * 64 + d;
                bf16x2 v2;
                v2[0] = V[gb];
                v2[1] = V[gb + KV_DIM];
                *(bf16x2*)&Vt[d * STV + k] = v2;
            }
        }
        __syncthreads();

        // ---- S = Q K^T (16 queries x 64 keys per wave) ----
        floatx4 s[4];
#pragma unroll
        for (int nt = 0; nt < 4; nt++) s[nt] = (floatx4)(0.0f);
#pragma unroll
        for (int ks = 0; ks < 2; ks++) {
#pragma unroll
            for (int nt = 0; nt < 4; nt++) {
                bf16x8 kf = *(const bf16x8*)&Ks[(nt * 16 + lr) * ST + ks * 32 + quad * 8];
                s[nt] = __builtin_amdgcn_mfma_f32_16x16x32_bf16(qf[ks], kf, s[nt], 0, 0, 0);
            }
        }

        // ---- mask + scale + row max ----
        float mt[4];
#pragma unroll
        for (int r = 0; r < 4; r++) mt[r] = -1e30f;
#pragma unroll
        for (int nt = 0; nt < 4; nt++) {
            int key = j0 + nt * 16 + lr;
#pragma unroll
            for (int r = 0; r < 4; r++) {
                int qi_ = q0 + wq + quad * 4 + r;
                bool valid = (key <= qi_) && (qi_ - key <= WINDOW);
                float val = valid ? s[nt][r] * 0.125f : -1e30f;
                s[nt][r] = val;
                mt[r] = fmaxf(mt[r], val);
            }
        }
#pragma unroll
        for (int r = 0; r < 4; r++) {
            mt[r] = fmaxf(mt[r], __shfl_xor(mt[r], 1));
            mt[r] = fmaxf(mt[r], __shfl_xor(mt[r], 2));
            mt[r] = fmaxf(mt[r], __shfl_xor(mt[r], 4));
            mt[r] = fmaxf(mt[r], __shfl_xor(mt[r], 8));
        }

        // ---- online softmax update; P -> LDS (bf16) ----
#pragma unroll
        for (int r = 0; r < 4; r++) {
            float mn = fmaxf(mrow[r], mt[r]);
            float alpha = __expf(mrow[r] - mn);
            mrow[r] = mn;
            float ls = 0.0f;
#pragma unroll
            for (int nt = 0; nt < 4; nt++) {
                float sv = s[nt][r];
                float p = (sv > -1e29f) ? __expf(sv - mn) : 0.0f;
                ls += p;
                Ps[(wq + quad * 4 + r) * ST + nt * 16 + lr] = (bf16)p;
            }
            ls += __shfl_xor(ls, 1);
            ls += __shfl_xor(ls, 2);
            ls += __shfl_xor(ls, 4);
            ls += __shfl_xor(ls, 8);
            lsum[r] = lsum[r] * alpha + ls;
#pragma unroll
            for (int nt = 0; nt < 4; nt++) o[nt][r] *= alpha;
        }

        // wave-local LDS RAW fence (DS ops in-order per wave; keep compiler honest)
        __asm__ volatile("s_waitcnt lgkmcnt(0)" ::: "memory");

        // ---- O += P V  (P rows q, Vt rows d, both k-contiguous) ----
#pragma unroll
        for (int ks = 0; ks < 2; ks++) {
            bf16x8 pf = *(const bf16x8*)&Ps[(wq + lr) * ST + ks * 32 + quad * 8];
#pragma unroll
            for (int nt = 0; nt < 4; nt++) {
                bf16x8 vf = *(const bf16x8*)&Vt[(nt * 16 + lr) * STV + ks * 32 + quad * 8];
                o[nt] = __builtin_amdgcn_mfma_f32_16x16x32_bf16(pf, vf, o[nt], 0, 0, 0);
            }
        }
    }

    // ---- epilogue: divide by l, store bf16 ----
#pragma unroll
    for (int r = 0; r < 4; r++) {
        float invl = 1.0f / lsum[r];
        int row = q0 + wq + quad * 4 + r;
#pragma unroll
        for (int nt = 0; nt < 4; nt++)
            AO[((size_t)(b * SEQ_T + row)) * D_MODEL + h * 64 + nt * 16 + lr] =
                (bf16)(o[nt][r] * invl);
    }
}

// ---------------------------------------------------------------------------
extern "C" void kernel_launch(void* const* d_in, const int* in_sizes, int n_in,
                              void* d_out, int out_size, void* d_ws, size_t ws_size,
                              hipStream_t stream)
{
    const void* x  = d_in[0];
    const void* WQ = d_in[1];
    const void* WK = d_in[2];
    const void* WV = d_in[3];
    const void* WO = d_in[4];
    const int* pos = (const int*)d_in[5];

    int*  flag = (int*)d_ws;
    char* ws   = (char*)d_ws + 256;
    bf16* Qw = (bf16*)ws;                                     //  8 MB [4096,1024]
    bf16* Kw = (bf16*)(ws + (size_t) 8 * 1024 * 1024);        //  2 MB [4096,256]
    bf16* Vw = (bf16*)(ws + (size_t)10 * 1024 * 1024);        //  2 MB [4096,256]
    bf16* AO = (bf16*)(ws + (size_t)12 * 1024 * 1024);        //  8 MB [4096,1024]

    detect_dtype<<<1, 256, 0, stream>>>((const unsigned*)x, flag);

    gemm_bt<<<dim3(D_MODEL / 128, M_ROWS / 128), 256, 0, stream>>>(
        x, WQ, Qw, M_ROWS, D_MODEL, D_MODEL, flag, 1, 1, 0);
    gemm_bt<<<dim3(KV_DIM / 128, M_ROWS / 128), 256, 0, stream>>>(
        x, WK, Kw, M_ROWS, KV_DIM, D_MODEL, flag, 1, 1, 0);
    gemm_bt<<<dim3(KV_DIM / 128, M_ROWS / 128), 256, 0, stream>>>(
        x, WV, Vw, M_ROWS, KV_DIM, D_MODEL, flag, 1, 1, 0);

    rope_kernel<<<(M_ROWS * NUM_HEADS * 32) / 256, 256, 0, stream>>>(
        Qw, pos, M_ROWS, NUM_HEADS);
    rope_kernel<<<(M_ROWS * NUM_GROUPS * 32) / 256, 256, 0, stream>>>(
        Kw, pos, M_ROWS, NUM_GROUPS);

    attn_mfma<<<dim3(SEQ_T / 64, BATCH * NUM_HEADS), 256, 0, stream>>>(
        Qw, Kw, Vw, AO);

    gemm_bt<<<dim3(D_MODEL / 128, M_ROWS / 128), 256, 0, stream>>>(
        AO, WO, d_out, M_ROWS, D_MODEL, D_MODEL, flag, 0, 1, 1);
}

// Round 5
// 194.038 us; speedup vs baseline: 4.2825x; 1.8550x over previous
//
#include <hip/hip_runtime.h>
#include <hip/hip_bf16.h>

typedef __bf16 bf16;
typedef __bf16 bf16x2 __attribute__((ext_vector_type(2)));
typedef __bf16 bf16x8 __attribute__((ext_vector_type(8)));
typedef float  floatx4 __attribute__((ext_vector_type(4)));

#define D_MODEL   1024
#define NUM_HEADS 16
#define NUM_GROUPS 4
#define DK        64
#define SEQ_T     2048
#define BATCH     2
#define M_ROWS    (BATCH*SEQ_T)   // 4096
#define WINDOW    512
#define KV_DIM    (NUM_GROUPS*DK) // 256
#define N_QKV     (D_MODEL + 2*KV_DIM)  // 1536

// async global->LDS, 16B per lane, wave-uniform LDS base (m97 pattern)
#define GLDS16(g, l)                                                          \
    __builtin_amdgcn_global_load_lds(                                         \
        (const __attribute__((address_space(1))) void*)(g),                   \
        (__attribute__((address_space(3))) void*)(l), 16, 0, 0)

// ---------------------------------------------------------------------------
// Runtime input-dtype probe: flag=1 -> bf16 inputs, flag=0 -> fp32 inputs.
// ---------------------------------------------------------------------------
__global__ void detect_dtype(const unsigned* __restrict__ x, int* __restrict__ flag)
{
    __shared__ int cnt;
    if (threadIdx.x == 0) cnt = 0;
    __syncthreads();
    int local = 0;
    for (int i = threadIdx.x; i < 1024; i += 256) {
        unsigned e = (x[i] >> 7) & 0xFFu;
        local += (e >= 100u && e <= 140u) ? 1 : 0;
    }
    atomicAdd(&cnt, local);
    __syncthreads();
    if (threadIdx.x == 0) flag[0] = (cnt > 512) ? 1 : 0;
}

// ---------------------------------------------------------------------------
// Convert fp32 (or copy bf16) -> bf16, 8 elems/thread.
// ---------------------------------------------------------------------------
__global__ __launch_bounds__(256)
void convert_bf16(const void* __restrict__ src, bf16* __restrict__ dst, int n,
                  const int* __restrict__ flag)
{
    const bool f32 = (flag[0] == 0);
    int i = (blockIdx.x * 256 + threadIdx.x) * 8;
    if (i >= n) return;
    bf16x8 v;
    if (f32) {
        const float* s = (const float*)src + i;
        float4 a = *(const float4*)s;
        float4 b = *(const float4*)(s + 4);
        v[0] = (bf16)a.x; v[1] = (bf16)a.y; v[2] = (bf16)a.z; v[3] = (bf16)a.w;
        v[4] = (bf16)b.x; v[5] = (bf16)b.y; v[6] = (bf16)b.z; v[7] = (bf16)b.w;
    } else {
        v = *(const bf16x8*)((const bf16*)src + i);
    }
    *(bf16x8*)&dst[i] = v;
}

// ---------------------------------------------------------------------------
// bf16 GEMM, C[M,N] = A[M,K] @ W[N,K]^T. 64x128 tile, 4 waves (2x2, each
// 32x64), BK=32, global_load_lds width-16 staging into unpadded LDS tiles.
// mode 0: split QKV outputs (bf16). mode 1: single output Co (fp32 if flag==0).
// ---------------------------------------------------------------------------
__global__ __launch_bounds__(256)
void gemm64(const bf16* __restrict__ A, const bf16* __restrict__ W, int K,
            bf16* __restrict__ Cq, bf16* __restrict__ Ck, bf16* __restrict__ Cv,
            void* __restrict__ Co, const int* __restrict__ flag, int mode, int N)
{
    __shared__ bf16 As[64 * 32];    // 4 KB, lane-order chunks
    __shared__ bf16 Bs[128 * 32];   // 8 KB

    const int tid  = threadIdx.x;
    const int wave = tid >> 6;
    const int lane = tid & 63;
    const int lr   = lane & 15;
    const int quad = lane >> 4;
    const int m0 = blockIdx.y * 64;
    const int n0 = blockIdx.x * 128;
    const int wm = (wave >> 1) * 32;
    const int wn = (wave & 1) * 64;

    // staging source addresses: chunk c covers rows c*16..c*16+15 of a 32-col
    // tile; lane L deposits 16 B at LDS elem c*512 + L*8 = row c*16+L/4,
    // col (L&3)*8 -> global row must match.
    const int srow = (lane >> 2);
    const int scol = (lane & 3) * 8;
    const bf16* Ap  = &A[(size_t)(m0 + wave * 16 + srow) * K + scol];
    const bf16* Wp0 = &W[(size_t)(n0 + wave * 16 + srow) * K + scol];
    const bf16* Wp1 = &W[(size_t)(n0 + 64 + wave * 16 + srow) * K + scol];
    bf16* Asd  = &As[wave * 512];
    bf16* Bsd0 = &Bs[wave * 512];
    bf16* Bsd1 = &Bs[(wave + 4) * 512];

    floatx4 acc[2][4];
#pragma unroll
    for (int i = 0; i < 2; i++)
#pragma unroll
        for (int j = 0; j < 4; j++) acc[i][j] = (floatx4)(0.0f);

    for (int k0 = 0; k0 < K; k0 += 32) {
        __syncthreads();                 // prev-iter readers done
        GLDS16(Ap + k0, Asd);
        GLDS16(Wp0 + k0, Bsd0);
        GLDS16(Wp1 + k0, Bsd1);
        __syncthreads();                 // deposits drained (vmcnt(0))

        bf16x8 af[2], bf_[4];
#pragma unroll
        for (int mi = 0; mi < 2; mi++)
            af[mi] = *(const bf16x8*)&As[(wm + mi * 16 + lr) * 32 + quad * 8];
#pragma unroll
        for (int ni = 0; ni < 4; ni++)
            bf_[ni] = *(const bf16x8*)&Bs[(wn + ni * 16 + lr) * 32 + quad * 8];

#pragma unroll
        for (int mi = 0; mi < 2; mi++)
#pragma unroll
            for (int ni = 0; ni < 4; ni++)
                acc[mi][ni] = __builtin_amdgcn_mfma_f32_16x16x32_bf16(
                    af[mi], bf_[ni], acc[mi][ni], 0, 0, 0);
    }

    if (mode == 0) {
        bf16* out; int ld, coff;
        if (n0 < D_MODEL)               { out = Cq; ld = D_MODEL; coff = n0; }
        else if (n0 < D_MODEL + KV_DIM) { out = Ck; ld = KV_DIM;  coff = n0 - D_MODEL; }
        else                            { out = Cv; ld = KV_DIM;  coff = n0 - D_MODEL - KV_DIM; }
#pragma unroll
        for (int mi = 0; mi < 2; mi++)
#pragma unroll
            for (int ni = 0; ni < 4; ni++)
#pragma unroll
                for (int r = 0; r < 4; r++) {
                    int row = m0 + wm + mi * 16 + quad * 4 + r;
                    int col = coff + wn + ni * 16 + lr;
                    out[(size_t)row * ld + col] = (bf16)acc[mi][ni][r];
                }
    } else {
        const bool c32 = (flag[0] == 0);
#pragma unroll
        for (int mi = 0; mi < 2; mi++)
#pragma unroll
            for (int ni = 0; ni < 4; ni++)
#pragma unroll
                for (int r = 0; r < 4; r++) {
                    int row = m0 + wm + mi * 16 + quad * 4 + r;
                    int col = n0 + wn + ni * 16 + lr;
                    float val = acc[mi][ni][r];
                    if (c32) ((float*)Co)[(size_t)row * N + col] = val;
                    else     ((bf16*)Co)[(size_t)row * N + col] = (bf16)val;
                }
    }
}

// ---------------------------------------------------------------------------
// RoPE, interleaved pairs, in-place on bf16 workspace (unchanged).
// ---------------------------------------------------------------------------
__global__ __launch_bounds__(256)
void rope_kernel(bf16* __restrict__ X, const int* __restrict__ pos,
                 int rows, int heads)
{
    int idx = blockIdx.x * 256 + threadIdx.x;
    int total = rows * heads * 32;
    if (idx >= total) return;
    int i   = idx & 31;
    int h   = (idx >> 5) % heads;
    int row = idx / (heads * 32);
    int t   = row & (SEQ_T - 1);
    float p   = (float)pos[t];
    float inv = exp2f(-(float)i * (13.287712379549449f / 32.0f));
    float ang = p * inv;
    float c = cosf(ang), s = sinf(ang);
    size_t base = (size_t)row * heads * 64 + (size_t)h * 64 + 2 * i;
    float x1 = (float)X[base], x2 = (float)X[base + 1];
    X[base]     = (bf16)(x1 * c - x2 * s);
    X[base + 1] = (bf16)(x1 * s + x2 * c);
}

// ---------------------------------------------------------------------------
// MFMA flash attention (unchanged from R4).
// ---------------------------------------------------------------------------
__global__ __launch_bounds__(256)
void attn_mfma(const bf16* __restrict__ Q, const bf16* __restrict__ K,
               const bf16* __restrict__ V, bf16* __restrict__ AO)
{
    const int ST = 80, STV = 72;
    __shared__ bf16 Qs[64 * ST];
    __shared__ bf16 Ks[64 * ST];
    __shared__ bf16 Ps[64 * ST];
    __shared__ bf16 Vt[64 * STV];

    const int tid  = threadIdx.x;
    const int wave = tid >> 6;
    const int lane = tid & 63;
    const int lr   = lane & 15;
    const int quad = lane >> 4;
    const int qt = blockIdx.x, bh = blockIdx.y;
    const int b = bh >> 4, h = bh & 15, g = h >> 2;
    const int q0 = qt * 64;
    const int wq = wave * 16;

#pragma unroll
    for (int i = 0; i < 2; i++) {
        int c = tid + i * 256;
        int row = c >> 3, col8 = (c & 7) * 8;
        *(bf16x8*)&Qs[row * ST + col8] =
            *(const bf16x8*)&Q[((size_t)(b * SEQ_T + q0 + row)) * D_MODEL + h * 64 + col8];
    }
    __syncthreads();

    bf16x8 qf[2];
#pragma unroll
    for (int ks = 0; ks < 2; ks++)
        qf[ks] = *(const bf16x8*)&Qs[(wq + lr) * ST + ks * 32 + quad * 8];

    float mrow[4], lsum[4];
    floatx4 o[4];
#pragma unroll
    for (int r = 0; r < 4; r++) { mrow[r] = -1e30f; lsum[r] = 0.0f; }
#pragma unroll
    for (int nt = 0; nt < 4; nt++) o[nt] = (floatx4)(0.0f);

    const int t0 = (q0 >= WINDOW) ? (q0 - WINDOW) : 0;

    for (int j0 = t0; j0 <= q0; j0 += 64) {
        __syncthreads();
#pragma unroll
        for (int i = 0; i < 2; i++) {
            int c = tid + i * 256;
            int row = c >> 3, col8 = (c & 7) * 8;
            *(bf16x8*)&Ks[row * ST + col8] =
                *(const bf16x8*)&K[((size_t)(b * SEQ_T + j0 + row)) * KV_DIM + g * 64 + col8];
        }
        {
            int d = tid & 63, kp = tid >> 6;
#pragma unroll
            for (int j = 0; j < 8; j++) {
                int k = kp * 16 + 2 * j;
                size_t gb = ((size_t)(b * SEQ_T + j0 + k)) * KV_DIM + g * 64 + d;
                bf16x2 v2;
                v2[0] = V[gb];
                v2[1] = V[gb + KV_DIM];
                *(bf16x2*)&Vt[d * STV + k] = v2;
            }
        }
        __syncthreads();

        floatx4 s[4];
#pragma unroll
        for (int nt = 0; nt < 4; nt++) s[nt] = (floatx4)(0.0f);
#pragma unroll
        for (int ks = 0; ks < 2; ks++) {
#pragma unroll
            for (int nt = 0; nt < 4; nt++) {
                bf16x8 kf = *(const bf16x8*)&Ks[(nt * 16 + lr) * ST + ks * 32 + quad * 8];
                s[nt] = __builtin_amdgcn_mfma_f32_16x16x32_bf16(qf[ks], kf, s[nt], 0, 0, 0);
            }
        }

        float mt[4];
#pragma unroll
        for (int r = 0; r < 4; r++) mt[r] = -1e30f;
#pragma unroll
        for (int nt = 0; nt < 4; nt++) {
            int key = j0 + nt * 16 + lr;
#pragma unroll
            for (int r = 0; r < 4; r++) {
                int qi_ = q0 + wq + quad * 4 + r;
                bool valid = (key <= qi_) && (qi_ - key <= WINDOW);
                float val = valid ? s[nt][r] * 0.125f : -1e30f;
                s[nt][r] = val;
                mt[r] = fmaxf(mt[r], val);
            }
        }
#pragma unroll
        for (int r = 0; r < 4; r++) {
            mt[r] = fmaxf(mt[r], __shfl_xor(mt[r], 1));
            mt[r] = fmaxf(mt[r], __shfl_xor(mt[r], 2));
            mt[r] = fmaxf(mt[r], __shfl_xor(mt[r], 4));
            mt[r] = fmaxf(mt[r], __shfl_xor(mt[r], 8));
        }

#pragma unroll
        for (int r = 0; r < 4; r++) {
            float mn = fmaxf(mrow[r], mt[r]);
            float alpha = __expf(mrow[r] - mn);
            mrow[r] = mn;
            float ls = 0.0f;
#pragma unroll
            for (int nt = 0; nt < 4; nt++) {
                float sv = s[nt][r];
                float p = (sv > -1e29f) ? __expf(sv - mn) : 0.0f;
                ls += p;
                Ps[(wq + quad * 4 + r) * ST + nt * 16 + lr] = (bf16)p;
            }
            ls += __shfl_xor(ls, 1);
            ls += __shfl_xor(ls, 2);
            ls += __shfl_xor(ls, 4);
            ls += __shfl_xor(ls, 8);
            lsum[r] = lsum[r] * alpha + ls;
#pragma unroll
            for (int nt = 0; nt < 4; nt++) o[nt][r] *= alpha;
        }

        __asm__ volatile("s_waitcnt lgkmcnt(0)" ::: "memory");

#pragma unroll
        for (int ks = 0; ks < 2; ks++) {
            bf16x8 pf = *(const bf16x8*)&Ps[(wq + lr) * ST + ks * 32 + quad * 8];
#pragma unroll
            for (int nt = 0; nt < 4; nt++) {
                bf16x8 vf = *(const bf16x8*)&Vt[(nt * 16 + lr) * STV + ks * 32 + quad * 8];
                o[nt] = __builtin_amdgcn_mfma_f32_16x16x32_bf16(pf, vf, o[nt], 0, 0, 0);
            }
        }
    }

#pragma unroll
    for (int r = 0; r < 4; r++) {
        float invl = 1.0f / lsum[r];
        int row = q0 + wq + quad * 4 + r;
#pragma unroll
        for (int nt = 0; nt < 4; nt++)
            AO[((size_t)(b * SEQ_T + row)) * D_MODEL + h * 64 + nt * 16 + lr] =
                (bf16)(o[nt][r] * invl);
    }
}

// ---------------------------------------------------------------------------
extern "C" void kernel_launch(void* const* d_in, const int* in_sizes, int n_in,
                              void* d_out, int out_size, void* d_ws, size_t ws_size,
                              hipStream_t stream)
{
    const void* x  = d_in[0];
    const void* WQ = d_in[1];
    const void* WK = d_in[2];
    const void* WV = d_in[3];
    const void* WO = d_in[4];
    const int* pos = (const int*)d_in[5];

    // ws: flag 256B | Qw 8MB | Kw 2MB | Vw 2MB | xb/AO 8MB | Wqkv 3MB | WOb 2MB
    int*  flag = (int*)d_ws;
    char* ws   = (char*)d_ws + 256;
    bf16* Qw   = (bf16*)ws;
    bf16* Kw   = (bf16*)(ws + (size_t) 8 * 1024 * 1024);
    bf16* Vw   = (bf16*)(ws + (size_t)10 * 1024 * 1024);
    bf16* xb   = (bf16*)(ws + (size_t)12 * 1024 * 1024);   // dead after QKV gemm
    bf16* AO   = xb;                                        // overlay
    bf16* Wqkv = (bf16*)(ws + (size_t)20 * 1024 * 1024);
    bf16* WOb  = (bf16*)(ws + (size_t)23 * 1024 * 1024);

    detect_dtype<<<1, 256, 0, stream>>>((const unsigned*)x, flag);

    // converts to bf16 (copy if already bf16)
    convert_bf16<<<(M_ROWS * D_MODEL) / 2048, 256, 0, stream>>>(x, xb, M_ROWS * D_MODEL, flag);
    convert_bf16<<<(D_MODEL * D_MODEL) / 2048, 256, 0, stream>>>(WQ, Wqkv, D_MODEL * D_MODEL, flag);
    convert_bf16<<<(KV_DIM * D_MODEL) / 2048, 256, 0, stream>>>(WK, Wqkv + (size_t)D_MODEL * D_MODEL, KV_DIM * D_MODEL, flag);
    convert_bf16<<<(KV_DIM * D_MODEL) / 2048, 256, 0, stream>>>(WV, Wqkv + (size_t)(D_MODEL + KV_DIM) * D_MODEL, KV_DIM * D_MODEL, flag);
    convert_bf16<<<(D_MODEL * D_MODEL) / 2048, 256, 0, stream>>>(WO, WOb, D_MODEL * D_MODEL, flag);

    // fused QKV projection: [4096,1536] = xb @ Wqkv^T, split-written
    gemm64<<<dim3(N_QKV / 128, M_ROWS / 64), 256, 0, stream>>>(
        xb, Wqkv, D_MODEL, Qw, Kw, Vw, nullptr, flag, 0, N_QKV);

    rope_kernel<<<(M_ROWS * NUM_HEADS * 32) / 256, 256, 0, stream>>>(
        Qw, pos, M_ROWS, NUM_HEADS);
    rope_kernel<<<(M_ROWS * NUM_GROUPS * 32) / 256, 256, 0, stream>>>(
        Kw, pos, M_ROWS, NUM_GROUPS);

    attn_mfma<<<dim3(SEQ_T / 64, BATCH * NUM_HEADS), 256, 0, stream>>>(
        Qw, Kw, Vw, AO);

    // output projection: d_out = AO @ WOb^T (fp32 store when inputs were fp32)
    gemm64<<<dim3(D_MODEL / 128, M_ROWS / 64), 256, 0, stream>>>(
        AO, WOb, D_MODEL, nullptr, nullptr, nullptr, d_out, flag, 1, D_MODEL);
}

// Round 6
// 181.524 us; speedup vs baseline: 4.5778x; 1.0689x over previous
//
#include <hip/hip_runtime.h>
#include <hip/hip_bf16.h>

typedef __bf16 bf16;
typedef __bf16 bf16x8 __attribute__((ext_vector_type(8)));
typedef float  floatx4 __attribute__((ext_vector_type(4)));

#define D_MODEL   1024
#define NUM_HEADS 16
#define NUM_GROUPS 4
#define DK        64
#define SEQ_T     2048
#define BATCH     2
#define M_ROWS    (BATCH*SEQ_T)   // 4096
#define WINDOW    512
#define KV_DIM    (NUM_GROUPS*DK) // 256
#define N_QKV     (D_MODEL + 2*KV_DIM)  // 1536
// Q pre-scale: 1/sqrt(64) * log2(e)  (exp -> exp2 domain)
#define QSCALE    0.1803368801111204f

#define GLDS16(g, l)                                                          \
    __builtin_amdgcn_global_load_lds(                                         \
        (const __attribute__((address_space(1))) void*)(g),                   \
        (__attribute__((address_space(3))) void*)(l), 16, 0, 0)

// ---------------------------------------------------------------------------
__global__ void detect_dtype(const unsigned* __restrict__ x, int* __restrict__ flag)
{
    __shared__ int cnt;
    if (threadIdx.x == 0) cnt = 0;
    __syncthreads();
    int local = 0;
    for (int i = threadIdx.x; i < 1024; i += 256) {
        unsigned e = (x[i] >> 7) & 0xFFu;
        local += (e >= 100u && e <= 140u) ? 1 : 0;
    }
    atomicAdd(&cnt, local);
    __syncthreads();
    if (threadIdx.x == 0) flag[0] = (cnt > 512) ? 1 : 0;
}

// ---------------------------------------------------------------------------
// One fused convert kernel: 5 segments (x, WQ, WK, WV, WO) -> bf16 dsts.
// One 8-elem chunk per thread.
// ---------------------------------------------------------------------------
__global__ __launch_bounds__(256)
void convert_all(const void* s0, bf16* d0, int c0,
                 const void* s1, bf16* d1, int c1,
                 const void* s2, bf16* d2, int c2,
                 const void* s3, bf16* d3, int c3,
                 const void* s4, bf16* d4, int c4,
                 const int* __restrict__ flag)
{
    int id = blockIdx.x * 256 + threadIdx.x;
    const void* src; bf16* dst;
    if      (id < c0)                     { src = s0; dst = d0; }
    else if ((id -= c0) < c1)             { src = s1; dst = d1; }
    else if ((id -= c1) < c2)             { src = s2; dst = d2; }
    else if ((id -= c2) < c3)             { src = s3; dst = d3; }
    else if ((id -= c3) < c4)             { src = s4; dst = d4; }
    else return;
    int i = id * 8;
    bf16x8 v;
    if (flag[0] == 0) {
        const float* s = (const float*)src + i;
        float4 a = *(const float4*)s;
        float4 b = *(const float4*)(s + 4);
        v[0] = (bf16)a.x; v[1] = (bf16)a.y; v[2] = (bf16)a.z; v[3] = (bf16)a.w;
        v[4] = (bf16)b.x; v[5] = (bf16)b.y; v[6] = (bf16)b.z; v[7] = (bf16)b.w;
    } else {
        v = *(const bf16x8*)((const bf16*)src + i);
    }
    *(bf16x8*)&dst[i] = v;
}

// ---------------------------------------------------------------------------
// bf16 GEMM (unchanged from R5): 64x128 tile, glds staging.
// ---------------------------------------------------------------------------
__global__ __launch_bounds__(256)
void gemm64(const bf16* __restrict__ A, const bf16* __restrict__ W, int K,
            bf16* __restrict__ Cq, bf16* __restrict__ Ck, bf16* __restrict__ Cv,
            void* __restrict__ Co, const int* __restrict__ flag, int mode, int N)
{
    __shared__ bf16 As[64 * 32];
    __shared__ bf16 Bs[128 * 32];

    const int tid  = threadIdx.x;
    const int wave = tid >> 6;
    const int lane = tid & 63;
    const int lr   = lane & 15;
    const int quad = lane >> 4;
    const int m0 = blockIdx.y * 64;
    const int n0 = blockIdx.x * 128;
    const int wm = (wave >> 1) * 32;
    const int wn = (wave & 1) * 64;

    const int srow = (lane >> 2);
    const int scol = (lane & 3) * 8;
    const bf16* Ap  = &A[(size_t)(m0 + wave * 16 + srow) * K + scol];
    const bf16* Wp0 = &W[(size_t)(n0 + wave * 16 + srow) * K + scol];
    const bf16* Wp1 = &W[(size_t)(n0 + 64 + wave * 16 + srow) * K + scol];
    bf16* Asd  = &As[wave * 512];
    bf16* Bsd0 = &Bs[wave * 512];
    bf16* Bsd1 = &Bs[(wave + 4) * 512];

    floatx4 acc[2][4];
#pragma unroll
    for (int i = 0; i < 2; i++)
#pragma unroll
        for (int j = 0; j < 4; j++) acc[i][j] = (floatx4)(0.0f);

    for (int k0 = 0; k0 < K; k0 += 32) {
        __syncthreads();
        GLDS16(Ap + k0, Asd);
        GLDS16(Wp0 + k0, Bsd0);
        GLDS16(Wp1 + k0, Bsd1);
        __syncthreads();

        bf16x8 af[2], bf_[4];
#pragma unroll
        for (int mi = 0; mi < 2; mi++)
            af[mi] = *(const bf16x8*)&As[(wm + mi * 16 + lr) * 32 + quad * 8];
#pragma unroll
        for (int ni = 0; ni < 4; ni++)
            bf_[ni] = *(const bf16x8*)&Bs[(wn + ni * 16 + lr) * 32 + quad * 8];

#pragma unroll
        for (int mi = 0; mi < 2; mi++)
#pragma unroll
            for (int ni = 0; ni < 4; ni++)
                acc[mi][ni] = __builtin_amdgcn_mfma_f32_16x16x32_bf16(
                    af[mi], bf_[ni], acc[mi][ni], 0, 0, 0);
    }

    if (mode == 0) {
        bf16* out; int ld, coff;
        if (n0 < D_MODEL)               { out = Cq; ld = D_MODEL; coff = n0; }
        else if (n0 < D_MODEL + KV_DIM) { out = Ck; ld = KV_DIM;  coff = n0 - D_MODEL; }
        else                            { out = Cv; ld = KV_DIM;  coff = n0 - D_MODEL - KV_DIM; }
#pragma unroll
        for (int mi = 0; mi < 2; mi++)
#pragma unroll
            for (int ni = 0; ni < 4; ni++)
#pragma unroll
                for (int r = 0; r < 4; r++) {
                    int row = m0 + wm + mi * 16 + quad * 4 + r;
                    int col = coff + wn + ni * 16 + lr;
                    out[(size_t)row * ld + col] = (bf16)acc[mi][ni][r];
                }
    } else {
        const bool c32 = (flag[0] == 0);
#pragma unroll
        for (int mi = 0; mi < 2; mi++)
#pragma unroll
            for (int ni = 0; ni < 4; ni++)
#pragma unroll
                for (int r = 0; r < 4; r++) {
                    int row = m0 + wm + mi * 16 + quad * 4 + r;
                    int col = n0 + wn + ni * 16 + lr;
                    float val = acc[mi][ni][r];
                    if (c32) ((float*)Co)[(size_t)row * N + col] = val;
                    else     ((bf16*)Co)[(size_t)row * N + col] = (bf16)val;
                }
    }
}

// ---------------------------------------------------------------------------
// Fused RoPE for Q (scaled by QSCALE) and K, in-place on bf16.
// ---------------------------------------------------------------------------
__global__ __launch_bounds__(256)
void rope_fused(bf16* __restrict__ Qw, bf16* __restrict__ Kw,
                const int* __restrict__ pos)
{
    const int qtotal = M_ROWS * NUM_HEADS * 32;
    int idx = blockIdx.x * 256 + threadIdx.x;
    bf16* X; int heads; float sc;
    if (idx < qtotal) { X = Qw; heads = NUM_HEADS; sc = QSCALE; }
    else {
        idx -= qtotal;
        X = Kw; heads = NUM_GROUPS; sc = 1.0f;
        if (idx >= M_ROWS * NUM_GROUPS * 32) return;
    }
    int i   = idx & 31;
    int h   = (idx >> 5) % heads;
    int row = idx / (heads * 32);
    int t   = row & (SEQ_T - 1);
    float p   = (float)pos[t];
    float inv = exp2f(-(float)i * (13.287712379549449f / 32.0f));
    float ang = p * inv;
    float c = cosf(ang), s = sinf(ang);
    size_t base = (size_t)row * heads * 64 + (size_t)h * 64 + 2 * i;
    float x1 = (float)X[base], x2 = (float)X[base + 1];
    X[base]     = (bf16)((x1 * c - x2 * s) * sc);
    X[base + 1] = (bf16)((x1 * s + x2 * c) * sc);
}

// ---------------------------------------------------------------------------
// V transpose: Vw[b*2048+t][g*64+d] -> Vt_glob[((b*4+g)*64+d)*2048 + t]
// 64x64 tiles, vector loads + vector stores via LDS.
// ---------------------------------------------------------------------------
__global__ __launch_bounds__(256)
void transpose_v(const bf16* __restrict__ Vw, bf16* __restrict__ Vt)
{
    __shared__ bf16 Ts[64 * 72];
    const int tid = threadIdx.x;
    const int bg = blockIdx.x >> 5;      // 0..7 = b*4+g
    const int tt = blockIdx.x & 31;
    const int b = bg >> 2, g = bg & 3;
    const int t0 = tt * 64;

#pragma unroll
    for (int i = 0; i < 2; i++) {
        int c = tid + i * 256;
        int trow = c >> 3, col8 = (c & 7) * 8;
        *(bf16x8*)&Ts[trow * 72 + col8] =
            *(const bf16x8*)&Vw[(size_t)(b * SEQ_T + t0 + trow) * KV_DIM + g * 64 + col8];
    }
    __syncthreads();
#pragma unroll
    for (int i = 0; i < 2; i++) {
        int c = tid + i * 256;
        int drow = c >> 3, tcol8 = (c & 7) * 8;
        bf16x8 v;
#pragma unroll
        for (int j = 0; j < 8; j++) v[j] = Ts[(tcol8 + j) * 72 + drow];
        *(bf16x8*)&Vt[((size_t)(bg * 64 + drow)) * SEQ_T + t0 + tcol8] = v;
    }
}

// ---------------------------------------------------------------------------
// MFMA flash attention. Block = 64 queries x one (b,h); 4 waves x 16 queries.
// Q pre-scaled by QSCALE (exp2 domain). Masking only on boundary tiles.
// Row-sum l accumulated via MFMA ones-column (5th n-tile of Vt).
// ---------------------------------------------------------------------------
__global__ __launch_bounds__(256)
void attn_mfma(const bf16* __restrict__ Q, const bf16* __restrict__ K,
               const bf16* __restrict__ Vt_g, bf16* __restrict__ AO)
{
    const int ST = 72;
    __shared__ bf16 Qs[64 * ST];
    __shared__ bf16 Ks[64 * ST];
    __shared__ bf16 Ps[64 * ST];
    __shared__ bf16 Vt[80 * ST];   // rows 0..63 staged; row 64 = ones

    const int tid  = threadIdx.x;
    const int wave = tid >> 6;
    const int lane = tid & 63;
    const int lr   = lane & 15;
    const int quad = lane >> 4;
    const int qt = blockIdx.x, bh = blockIdx.y;
    const int b = bh >> 4, h = bh & 15, g = h >> 2;
    const int q0 = qt * 64;
    const int wq = wave * 16;

    // stage Q; init ones row (64) of Vt; rows 65..79 zeroed (safety)
#pragma unroll
    for (int i = 0; i < 2; i++) {
        int c = tid + i * 256;
        int row = c >> 3, col8 = (c & 7) * 8;
        *(bf16x8*)&Qs[row * ST + col8] =
            *(const bf16x8*)&Q[((size_t)(b * SEQ_T + q0 + row)) * D_MODEL + h * 64 + col8];
    }
    for (int i = tid; i < 16 * ST; i += 256) Vt[64 * ST + i] = (bf16)0.0f;
    __syncthreads();
    if (tid < 64) Vt[64 * ST + tid] = (bf16)1.0f;
    __syncthreads();

    bf16x8 qf[2];
#pragma unroll
    for (int ks = 0; ks < 2; ks++)
        qf[ks] = *(const bf16x8*)&Qs[(wq + lr) * ST + ks * 32 + quad * 8];

    float mrow[4];
    floatx4 o[5];
#pragma unroll
    for (int r = 0; r < 4; r++) mrow[r] = -1e30f;
#pragma unroll
    for (int nt = 0; nt < 5; nt++) o[nt] = (floatx4)(0.0f);

    const int t0 = (q0 >= WINDOW) ? (q0 - WINDOW) : 0;

    for (int j0 = t0; j0 <= q0; j0 += 64) {
        const bool mC = (j0 == q0);                     // causal boundary tile
        const bool mW = (q0 >= WINDOW) && (j0 == t0);   // window boundary tile
        __syncthreads();
        // stage K tile and Vt tile (both vectorized, 2 chunks/thread each)
#pragma unroll
        for (int i = 0; i < 2; i++) {
            int c = tid + i * 256;
            int row = c >> 3, col8 = (c & 7) * 8;
            *(bf16x8*)&Ks[row * ST + col8] =
                *(const bf16x8*)&K[((size_t)(b * SEQ_T + j0 + row)) * KV_DIM + g * 64 + col8];
            *(bf16x8*)&Vt[row * ST + col8] =
                *(const bf16x8*)&Vt_g[((size_t)((b * NUM_GROUPS + g) * 64 + row)) * SEQ_T + j0 + col8];
        }
        __syncthreads();

        // S = Q K^T
        floatx4 s[4];
#pragma unroll
        for (int nt = 0; nt < 4; nt++) s[nt] = (floatx4)(0.0f);
#pragma unroll
        for (int ks = 0; ks < 2; ks++) {
#pragma unroll
            for (int nt = 0; nt < 4; nt++) {
                bf16x8 kf = *(const bf16x8*)&Ks[(nt * 16 + lr) * ST + ks * 32 + quad * 8];
                s[nt] = __builtin_amdgcn_mfma_f32_16x16x32_bf16(qf[ks], kf, s[nt], 0, 0, 0);
            }
        }

        // boundary masking only (wave-uniform branch)
        if (mC) {
#pragma unroll
            for (int nt = 0; nt < 4; nt++) {
                int key = j0 + nt * 16 + lr;
#pragma unroll
                for (int r = 0; r < 4; r++) {
                    int qi_ = q0 + wq + quad * 4 + r;
                    s[nt][r] = (key <= qi_) ? s[nt][r] : -1e30f;
                }
            }
        } else if (mW) {
#pragma unroll
            for (int nt = 0; nt < 4; nt++) {
                int key = j0 + nt * 16 + lr;
#pragma unroll
                for (int r = 0; r < 4; r++) {
                    int qi_ = q0 + wq + quad * 4 + r;
                    s[nt][r] = (qi_ - key <= WINDOW) ? s[nt][r] : -1e30f;
                }
            }
        }

        // row max (16 lanes within quad group)
        float mt[4];
#pragma unroll
        for (int r = 0; r < 4; r++)
            mt[r] = fmaxf(fmaxf(s[0][r], s[1][r]), fmaxf(s[2][r], s[3][r]));
#pragma unroll
        for (int r = 0; r < 4; r++) {
            mt[r] = fmaxf(mt[r], __shfl_xor(mt[r], 1));
            mt[r] = fmaxf(mt[r], __shfl_xor(mt[r], 2));
            mt[r] = fmaxf(mt[r], __shfl_xor(mt[r], 4));
            mt[r] = fmaxf(mt[r], __shfl_xor(mt[r], 8));
        }

        // online softmax (exp2 domain): p -> Ps, o *= alpha
#pragma unroll
        for (int r = 0; r < 4; r++) {
            float mn = fmaxf(mrow[r], mt[r]);
            float alpha = exp2f(mrow[r] - mn);
            mrow[r] = mn;
#pragma unroll
            for (int nt = 0; nt < 4; nt++) {
                float p = exp2f(s[nt][r] - mn);
                Ps[(wq + quad * 4 + r) * ST + nt * 16 + lr] = (bf16)p;
            }
#pragma unroll
            for (int nt = 0; nt < 5; nt++) o[nt][r] *= alpha;
        }

        __asm__ volatile("s_waitcnt lgkmcnt(0)" ::: "memory");

        // O += P V ; 5th n-tile accumulates row-sum l via ones row
#pragma unroll
        for (int ks = 0; ks < 2; ks++) {
            bf16x8 pf = *(const bf16x8*)&Ps[(wq + lr) * ST + ks * 32 + quad * 8];
#pragma unroll
            for (int nt = 0; nt < 5; nt++) {
                bf16x8 vf = *(const bf16x8*)&Vt[(nt * 16 + lr) * ST + ks * 32 + quad * 8];
                o[nt] = __builtin_amdgcn_mfma_f32_16x16x32_bf16(pf, vf, o[nt], 0, 0, 0);
            }
        }
    }

    // epilogue: l = o[4] at col 64 (lane lr==0 of each quad group)
#pragma unroll
    for (int r = 0; r < 4; r++) {
        float l = __shfl(o[4][r], lane & 48);
        float invl = 1.0f / l;
        int row = q0 + wq + quad * 4 + r;
#pragma unroll
        for (int nt = 0; nt < 4; nt++)
            AO[((size_t)(b * SEQ_T + row)) * D_MODEL + h * 64 + nt * 16 + lr] =
                (bf16)(o[nt][r] * invl);
    }
}

// ---------------------------------------------------------------------------
extern "C" void kernel_launch(void* const* d_in, const int* in_sizes, int n_in,
                              void* d_out, int out_size, void* d_ws, size_t ws_size,
                              hipStream_t stream)
{
    const void* x  = d_in[0];
    const void* WQ = d_in[1];
    const void* WK = d_in[2];
    const void* WV = d_in[3];
    const void* WO = d_in[4];
    const int* pos = (const int*)d_in[5];

    // ws: flag 256B | Qw 8MB | Kw 2MB | Vw 2MB | xb/AO 8MB | Wqkv/Vt_glob 3MB | WOb 2MB
    int*  flag = (int*)d_ws;
    char* ws   = (char*)d_ws + 256;
    bf16* Qw   = (bf16*)ws;
    bf16* Kw   = (bf16*)(ws + (size_t) 8 * 1024 * 1024);
    bf16* Vw   = (bf16*)(ws + (size_t)10 * 1024 * 1024);
    bf16* xb   = (bf16*)(ws + (size_t)12 * 1024 * 1024);
    bf16* AO   = xb;                                        // overlay (xb dead)
    bf16* Wqkv = (bf16*)(ws + (size_t)20 * 1024 * 1024);
    bf16* Vt_g = Wqkv;                                      // overlay (Wqkv dead)
    bf16* WOb  = (bf16*)(ws + (size_t)23 * 1024 * 1024);

    detect_dtype<<<1, 256, 0, stream>>>((const unsigned*)x, flag);

    const int cx = (M_ROWS * D_MODEL) / 8;     // 524288
    const int cq = (D_MODEL * D_MODEL) / 8;    // 131072
    const int ck = (KV_DIM * D_MODEL) / 8;     // 32768
    const int ctot = cx + cq + 2 * ck + cq;    // 851968
    convert_all<<<ctot / 256, 256, 0, stream>>>(
        x, xb, cx,
        WQ, Wqkv, cq,
        WK, Wqkv + (size_t)D_MODEL * D_MODEL, ck,
        WV, Wqkv + (size_t)(D_MODEL + KV_DIM) * D_MODEL, ck,
        WO, WOb, cq, flag);

    gemm64<<<dim3(N_QKV / 128, M_ROWS / 64), 256, 0, stream>>>(
        xb, Wqkv, D_MODEL, Qw, Kw, Vw, nullptr, flag, 0, N_QKV);

    rope_fused<<<(M_ROWS * (NUM_HEADS + NUM_GROUPS) * 32) / 256, 256, 0, stream>>>(
        Qw, Kw, pos);

    transpose_v<<<256, 256, 0, stream>>>(Vw, Vt_g);

    attn_mfma<<<dim3(SEQ_T / 64, BATCH * NUM_HEADS), 256, 0, stream>>>(
        Qw, Kw, Vt_g, AO);

    gemm64<<<dim3(D_MODEL / 128, M_ROWS / 64), 256, 0, stream>>>(
        AO, WOb, D_MODEL, nullptr, nullptr, nullptr, d_out, flag, 1, D_MODEL);
}

// Round 7
// 155.971 us; speedup vs baseline: 5.3277x; 1.1638x over previous
//
#include <hip/hip_runtime.h>
#include <hip/hip_bf16.h>

typedef __bf16 bf16;
typedef __bf16 bf16x8 __attribute__((ext_vector_type(8)));
typedef float  floatx4 __attribute__((ext_vector_type(4)));

#define D_MODEL   1024
#define NUM_HEADS 16
#define NUM_GROUPS 4
#define DK        64
#define SEQ_T     2048
#define BATCH     2
#define M_ROWS    (BATCH*SEQ_T)   // 4096
#define WINDOW    512
#define KV_DIM    (NUM_GROUPS*DK) // 256
#define N_QKV     (D_MODEL + 2*KV_DIM)  // 1536
// Q pre-scale: 1/sqrt(64) * log2(e)  (exp -> exp2 domain)
#define QSCALE    0.1803368801111204f
// log2(10000)/32
#define FREQ_C    0.4152410118609203f

#define GLDS16(g, l)                                                          \
    __builtin_amdgcn_global_load_lds(                                         \
        (const __attribute__((address_space(1))) void*)(g),                   \
        (__attribute__((address_space(3))) void*)(l), 16, 0, 0)

// ---------------------------------------------------------------------------
// Fused convert: 5 fp32 segments (x, WQ, WK, WV, WO) -> bf16 dsts.
// ---------------------------------------------------------------------------
__global__ __launch_bounds__(256)
void convert_all(const float* s0, bf16* d0, int c0,
                 const float* s1, bf16* d1, int c1,
                 const float* s2, bf16* d2, int c2,
                 const float* s3, bf16* d3, int c3,
                 const float* s4, bf16* d4, int c4)
{
    int id = blockIdx.x * 256 + threadIdx.x;
    const float* src; bf16* dst;
    if      (id < c0)         { src = s0; dst = d0; }
    else if ((id -= c0) < c1) { src = s1; dst = d1; }
    else if ((id -= c1) < c2) { src = s2; dst = d2; }
    else if ((id -= c2) < c3) { src = s3; dst = d3; }
    else if ((id -= c3) < c4) { src = s4; dst = d4; }
    else return;
    int i = id * 8;
    const float* s = src + i;
    float4 a = *(const float4*)s;
    float4 b = *(const float4*)(s + 4);
    bf16x8 v;
    v[0] = (bf16)a.x; v[1] = (bf16)a.y; v[2] = (bf16)a.z; v[3] = (bf16)a.w;
    v[4] = (bf16)b.x; v[5] = (bf16)b.y; v[6] = (bf16)b.z; v[7] = (bf16)b.w;
    *(bf16x8*)&dst[i] = v;
}

// ---------------------------------------------------------------------------
// bf16 GEMM, C = A @ W^T. 64x128 tile, 4 waves (2x2 of 32x64), BK=64 as two
// BK=32 half-tiles (proven glds layout), 16 MFMA per barrier pair.
// mode 0: split QKV outputs with fused RoPE (+QSCALE on Q).
// mode 1: single fp32 output Co.
// ---------------------------------------------------------------------------
__global__ __launch_bounds__(256)
void gemm64(const bf16* __restrict__ A, const bf16* __restrict__ W, int K,
            bf16* __restrict__ Cq, bf16* __restrict__ Ck, bf16* __restrict__ Cv,
            float* __restrict__ Co, const int* __restrict__ pos, int mode, int N)
{
    __shared__ bf16 As0[64 * 32], As1[64 * 32];     // 4 KB each
    __shared__ bf16 Bs0[128 * 32], Bs1[128 * 32];   // 8 KB each

    const int tid  = threadIdx.x;
    const int wave = tid >> 6;
    const int lane = tid & 63;
    const int lr   = lane & 15;
    const int quad = lane >> 4;
    const int m0 = blockIdx.y * 64;
    const int n0 = blockIdx.x * 128;
    const int wm = (wave >> 1) * 32;
    const int wn = (wave & 1) * 64;

    // staging: chunk = 16 rows x 32 cols; lane L -> row L>>2, col (L&3)*8
    const int srow = (lane >> 2);
    const int scol = (lane & 3) * 8;
    const bf16* Ap  = &A[(size_t)(m0 + wave * 16 + srow) * K + scol];
    const bf16* Wp0 = &W[(size_t)(n0 + wave * 16 + srow) * K + scol];
    const bf16* Wp1 = &W[(size_t)(n0 + 64 + wave * 16 + srow) * K + scol];
    bf16* As0d  = &As0[wave * 512];
    bf16* As1d  = &As1[wave * 512];
    bf16* Bs0d0 = &Bs0[wave * 512];
    bf16* Bs0d1 = &Bs0[(wave + 4) * 512];
    bf16* Bs1d0 = &Bs1[wave * 512];
    bf16* Bs1d1 = &Bs1[(wave + 4) * 512];

    floatx4 acc[2][4];
#pragma unroll
    for (int i = 0; i < 2; i++)
#pragma unroll
        for (int j = 0; j < 4; j++) acc[i][j] = (floatx4)(0.0f);

    for (int k0 = 0; k0 < K; k0 += 64) {
        __syncthreads();
        GLDS16(Ap + k0,       As0d);
        GLDS16(Ap + k0 + 32,  As1d);
        GLDS16(Wp0 + k0,      Bs0d0);
        GLDS16(Wp1 + k0,      Bs0d1);
        GLDS16(Wp0 + k0 + 32, Bs1d0);
        GLDS16(Wp1 + k0 + 32, Bs1d1);
        __syncthreads();

        bf16x8 a0[2], a1[2], b0[4], b1[4];
#pragma unroll
        for (int mi = 0; mi < 2; mi++) {
            a0[mi] = *(const bf16x8*)&As0[(wm + mi * 16 + lr) * 32 + quad * 8];
            a1[mi] = *(const bf16x8*)&As1[(wm + mi * 16 + lr) * 32 + quad * 8];
        }
#pragma unroll
        for (int ni = 0; ni < 4; ni++) {
            b0[ni] = *(const bf16x8*)&Bs0[(wn + ni * 16 + lr) * 32 + quad * 8];
            b1[ni] = *(const bf16x8*)&Bs1[(wn + ni * 16 + lr) * 32 + quad * 8];
        }

#pragma unroll
        for (int mi = 0; mi < 2; mi++)
#pragma unroll
            for (int ni = 0; ni < 4; ni++) {
                acc[mi][ni] = __builtin_amdgcn_mfma_f32_16x16x32_bf16(
                    a0[mi], b0[ni], acc[mi][ni], 0, 0, 0);
                acc[mi][ni] = __builtin_amdgcn_mfma_f32_16x16x32_bf16(
                    a1[mi], b1[ni], acc[mi][ni], 0, 0, 0);
            }
    }

    if (mode == 0) {
        bf16* out; int ld, coff;
        if (n0 < D_MODEL)               { out = Cq; ld = D_MODEL; coff = n0; }
        else if (n0 < D_MODEL + KV_DIM) { out = Ck; ld = KV_DIM;  coff = n0 - D_MODEL; }
        else                            { out = Cv; ld = KV_DIM;  coff = n0 - D_MODEL - KV_DIM; }
        const bool rope = (n0 < D_MODEL + KV_DIM);   // Q and K tiles
        const float sc  = (n0 < D_MODEL) ? QSCALE : 1.0f;
        float inv[4];
        float sgn = (lr & 1) ? 1.0f : -1.0f;
        if (rope) {
#pragma unroll
            for (int ni = 0; ni < 4; ni++) {
                int ip = (ni * 16 + lr) >> 1;        // pair index 0..31
                inv[ni] = exp2f(-(float)ip * FREQ_C);
            }
        }
#pragma unroll
        for (int mi = 0; mi < 2; mi++) {
#pragma unroll
            for (int r = 0; r < 4; r++) {
                int row = m0 + wm + mi * 16 + quad * 4 + r;
                float p = rope ? (float)pos[row & (SEQ_T - 1)] : 0.0f;
#pragma unroll
                for (int ni = 0; ni < 4; ni++) {
                    float v = acc[mi][ni][r];
                    if (rope) {
                        float vp = __shfl_xor(v, 1);
                        float ang = p * inv[ni];
                        float ss, cc;
                        __sincosf(ang, &ss, &cc);
                        v = v * cc + vp * ss * sgn;  // even: x1 c - x2 s ; odd: x1 s + x2 c
                    }
                    out[(size_t)row * ld + coff + wn + ni * 16 + lr] = (bf16)(v * sc);
                }
            }
        }
    } else {
#pragma unroll
        for (int mi = 0; mi < 2; mi++)
#pragma unroll
            for (int ni = 0; ni < 4; ni++)
#pragma unroll
                for (int r = 0; r < 4; r++) {
                    int row = m0 + wm + mi * 16 + quad * 4 + r;
                    int col = n0 + wn + ni * 16 + lr;
                    Co[(size_t)row * N + col] = acc[mi][ni][r];
                }
    }
}

// ---------------------------------------------------------------------------
// V transpose: Vw[b*2048+t][g*64+d] -> Vt[((b*4+g)*64+d)*2048 + t]
// ---------------------------------------------------------------------------
__global__ __launch_bounds__(256)
void transpose_v(const bf16* __restrict__ Vw, bf16* __restrict__ Vt)
{
    __shared__ bf16 Ts[64 * 72];
    const int tid = threadIdx.x;
    const int bg = blockIdx.x >> 5;
    const int tt = blockIdx.x & 31;
    const int b = bg >> 2, g = bg & 3;
    const int t0 = tt * 64;

#pragma unroll
    for (int i = 0; i < 2; i++) {
        int c = tid + i * 256;
        int trow = c >> 3, col8 = (c & 7) * 8;
        *(bf16x8*)&Ts[trow * 72 + col8] =
            *(const bf16x8*)&Vw[(size_t)(b * SEQ_T + t0 + trow) * KV_DIM + g * 64 + col8];
    }
    __syncthreads();
#pragma unroll
    for (int i = 0; i < 2; i++) {
        int c = tid + i * 256;
        int drow = c >> 3, tcol8 = (c & 7) * 8;
        bf16x8 v;
#pragma unroll
        for (int j = 0; j < 8; j++) v[j] = Ts[(tcol8 + j) * 72 + drow];
        *(bf16x8*)&Vt[((size_t)(bg * 64 + drow)) * SEQ_T + t0 + tcol8] = v;
    }
}

// ---------------------------------------------------------------------------
// MFMA flash attention, no-max softmax (Q pre-scaled to exp2 domain; scores
// Cauchy-Schwarz-bounded so exp2 can't overflow; o/l renormalizes exactly).
// Row-sum l via MFMA ones-column (5th n-tile). Masking only boundary tiles.
// ---------------------------------------------------------------------------
__global__ __launch_bounds__(256)
void attn_mfma(const bf16* __restrict__ Q, const bf16* __restrict__ K,
               const bf16* __restrict__ Vt_g, bf16* __restrict__ AO)
{
    const int ST = 72;
    __shared__ bf16 Qs[64 * ST];
    __shared__ bf16 Ks[64 * ST];
    __shared__ bf16 Ps[64 * ST];
    __shared__ bf16 Vt[80 * ST];   // rows 0..63 staged; row 64 = ones

    const int tid  = threadIdx.x;
    const int wave = tid >> 6;
    const int lane = tid & 63;
    const int lr   = lane & 15;
    const int quad = lane >> 4;
    const int qt = blockIdx.x, bh = blockIdx.y;
    const int b = bh >> 4, h = bh & 15, g = h >> 2;
    const int q0 = qt * 64;
    const int wq = wave * 16;

#pragma unroll
    for (int i = 0; i < 2; i++) {
        int c = tid + i * 256;
        int row = c >> 3, col8 = (c & 7) * 8;
        *(bf16x8*)&Qs[row * ST + col8] =
            *(const bf16x8*)&Q[((size_t)(b * SEQ_T + q0 + row)) * D_MODEL + h * 64 + col8];
    }
    for (int i = tid; i < 16 * ST; i += 256) Vt[64 * ST + i] = (bf16)0.0f;
    __syncthreads();
    if (tid < 64) Vt[64 * ST + tid] = (bf16)1.0f;
    __syncthreads();

    bf16x8 qf[2];
#pragma unroll
    for (int ks = 0; ks < 2; ks++)
        qf[ks] = *(const bf16x8*)&Qs[(wq + lr) * ST + ks * 32 + quad * 8];

    floatx4 o[5];
#pragma unroll
    for (int nt = 0; nt < 5; nt++) o[nt] = (floatx4)(0.0f);

    const int t0 = (q0 >= WINDOW) ? (q0 - WINDOW) : 0;

    for (int j0 = t0; j0 <= q0; j0 += 64) {
        const bool mC = (j0 == q0);
        const bool mW = (q0 >= WINDOW) && (j0 == t0);
        __syncthreads();
#pragma unroll
        for (int i = 0; i < 2; i++) {
            int c = tid + i * 256;
            int row = c >> 3, col8 = (c & 7) * 8;
            *(bf16x8*)&Ks[row * ST + col8] =
                *(const bf16x8*)&K[((size_t)(b * SEQ_T + j0 + row)) * KV_DIM + g * 64 + col8];
            *(bf16x8*)&Vt[row * ST + col8] =
                *(const bf16x8*)&Vt_g[((size_t)((b * NUM_GROUPS + g) * 64 + row)) * SEQ_T + j0 + col8];
        }
        __syncthreads();

        // S = Q K^T
        floatx4 s[4];
#pragma unroll
        for (int nt = 0; nt < 4; nt++) s[nt] = (floatx4)(0.0f);
#pragma unroll
        for (int ks = 0; ks < 2; ks++) {
#pragma unroll
            for (int nt = 0; nt < 4; nt++) {
                bf16x8 kf = *(const bf16x8*)&Ks[(nt * 16 + lr) * ST + ks * 32 + quad * 8];
                s[nt] = __builtin_amdgcn_mfma_f32_16x16x32_bf16(qf[ks], kf, s[nt], 0, 0, 0);
            }
        }

        if (mC) {
#pragma unroll
            for (int nt = 0; nt < 4; nt++) {
                int key = j0 + nt * 16 + lr;
#pragma unroll
                for (int r = 0; r < 4; r++) {
                    int qi_ = q0 + wq + quad * 4 + r;
                    s[nt][r] = (key <= qi_) ? s[nt][r] : -1e30f;
                }
            }
        } else if (mW) {
#pragma unroll
            for (int nt = 0; nt < 4; nt++) {
                int key = j0 + nt * 16 + lr;
#pragma unroll
                for (int r = 0; r < 4; r++) {
                    int qi_ = q0 + wq + quad * 4 + r;
                    s[nt][r] = (qi_ - key <= WINDOW) ? s[nt][r] : -1e30f;
                }
            }
        }

        // p = exp2(s), no max subtraction
#pragma unroll
        for (int nt = 0; nt < 4; nt++)
#pragma unroll
            for (int r = 0; r < 4; r++)
                Ps[(wq + quad * 4 + r) * ST + nt * 16 + lr] = (bf16)exp2f(s[nt][r]);

        __asm__ volatile("s_waitcnt lgkmcnt(0)" ::: "memory");

        // O += P V ; 5th n-tile accumulates l
#pragma unroll
        for (int ks = 0; ks < 2; ks++) {
            bf16x8 pf = *(const bf16x8*)&Ps[(wq + lr) * ST + ks * 32 + quad * 8];
#pragma unroll
            for (int nt = 0; nt < 5; nt++) {
                bf16x8 vf = *(const bf16x8*)&Vt[(nt * 16 + lr) * ST + ks * 32 + quad * 8];
                o[nt] = __builtin_amdgcn_mfma_f32_16x16x32_bf16(pf, vf, o[nt], 0, 0, 0);
            }
        }
    }

#pragma unroll
    for (int r = 0; r < 4; r++) {
        float l = __shfl(o[4][r], lane & 48);
        float invl = 1.0f / l;
        int row = q0 + wq + quad * 4 + r;
#pragma unroll
        for (int nt = 0; nt < 4; nt++)
            AO[((size_t)(b * SEQ_T + row)) * D_MODEL + h * 64 + nt * 16 + lr] =
                (bf16)(o[nt][r] * invl);
    }
}

// ---------------------------------------------------------------------------
extern "C" void kernel_launch(void* const* d_in, const int* in_sizes, int n_in,
                              void* d_out, int out_size, void* d_ws, size_t ws_size,
                              hipStream_t stream)
{
    const float* x  = (const float*)d_in[0];
    const float* WQ = (const float*)d_in[1];
    const float* WK = (const float*)d_in[2];
    const float* WV = (const float*)d_in[3];
    const float* WO = (const float*)d_in[4];
    const int*  pos = (const int*)d_in[5];

    // ws: Qw 8MB | Kw 2MB | Vw 2MB | xb/AO 8MB | Wqkv/Vt_g 3MB | WOb 2MB
    char* ws   = (char*)d_ws;
    bf16* Qw   = (bf16*)ws;
    bf16* Kw   = (bf16*)(ws + (size_t) 8 * 1024 * 1024);
    bf16* Vw   = (bf16*)(ws + (size_t)10 * 1024 * 1024);
    bf16* xb   = (bf16*)(ws + (size_t)12 * 1024 * 1024);
    bf16* AO   = xb;                                        // overlay (xb dead)
    bf16* Wqkv = (bf16*)(ws + (size_t)20 * 1024 * 1024);
    bf16* Vt_g = Wqkv;                                      // overlay (Wqkv dead)
    bf16* WOb  = (bf16*)(ws + (size_t)23 * 1024 * 1024);

    const int cx = (M_ROWS * D_MODEL) / 8;
    const int cq = (D_MODEL * D_MODEL) / 8;
    const int ck = (KV_DIM * D_MODEL) / 8;
    const int ctot = cx + cq + 2 * ck + cq;
    convert_all<<<ctot / 256, 256, 0, stream>>>(
        x, xb, cx,
        WQ, Wqkv, cq,
        WK, Wqkv + (size_t)D_MODEL * D_MODEL, ck,
        WV, Wqkv + (size_t)(D_MODEL + KV_DIM) * D_MODEL, ck,
        WO, WOb, cq);

    // fused QKV projection + RoPE(+QSCALE) epilogue
    gemm64<<<dim3(N_QKV / 128, M_ROWS / 64), 256, 0, stream>>>(
        xb, Wqkv, D_MODEL, Qw, Kw, Vw, nullptr, pos, 0, N_QKV);

    transpose_v<<<256, 256, 0, stream>>>(Vw, Vt_g);

    attn_mfma<<<dim3(SEQ_T / 64, BATCH * NUM_HEADS), 256, 0, stream>>>(
        Qw, Kw, Vt_g, AO);

    // output projection -> fp32 d_out
    gemm64<<<dim3(D_MODEL / 128, M_ROWS / 64), 256, 0, stream>>>(
        AO, WOb, D_MODEL, nullptr, nullptr, nullptr, (float*)d_out, pos, 1, D_MODEL);
}

// Round 8
// 155.507 us; speedup vs baseline: 5.3436x; 1.0030x over previous
//
#include <hip/hip_runtime.h>
#include <hip/hip_bf16.h>

typedef __bf16 bf16;
typedef __bf16 bf16x8 __attribute__((ext_vector_type(8)));
typedef float  floatx4 __attribute__((ext_vector_type(4)));

#define D_MODEL   1024
#define NUM_HEADS 16
#define NUM_GROUPS 4
#define DK        64
#define SEQ_T     2048
#define BATCH     2
#define M_ROWS    (BATCH*SEQ_T)   // 4096
#define WINDOW    512
#define KV_DIM    (NUM_GROUPS*DK) // 256
#define N_QKV     (D_MODEL + 2*KV_DIM)  // 1536
// Q pre-scale: 1/sqrt(64) * log2(e)  (exp -> exp2 domain)
#define QSCALE    0.1803368801111204f
// log2(10000)/32
#define FREQ_C    0.4152410118609203f

#define GLDS16(g, l)                                                          \
    __builtin_amdgcn_global_load_lds(                                         \
        (const __attribute__((address_space(1))) void*)(g),                   \
        (__attribute__((address_space(3))) void*)(l), 16, 0, 0)

// ---------------------------------------------------------------------------
// Fused convert: 5 fp32 segments (x, WQ, WK, WV, WO) -> bf16 dsts.
// ---------------------------------------------------------------------------
__global__ __launch_bounds__(256)
void convert_all(const float* s0, bf16* d0, int c0,
                 const float* s1, bf16* d1, int c1,
                 const float* s2, bf16* d2, int c2,
                 const float* s3, bf16* d3, int c3,
                 const float* s4, bf16* d4, int c4)
{
    int id = blockIdx.x * 256 + threadIdx.x;
    const float* src; bf16* dst;
    if      (id < c0)         { src = s0; dst = d0; }
    else if ((id -= c0) < c1) { src = s1; dst = d1; }
    else if ((id -= c1) < c2) { src = s2; dst = d2; }
    else if ((id -= c2) < c3) { src = s3; dst = d3; }
    else if ((id -= c3) < c4) { src = s4; dst = d4; }
    else return;
    int i = id * 8;
    const float* s = src + i;
    float4 a = *(const float4*)s;
    float4 b = *(const float4*)(s + 4);
    bf16x8 v;
    v[0] = (bf16)a.x; v[1] = (bf16)a.y; v[2] = (bf16)a.z; v[3] = (bf16)a.w;
    v[4] = (bf16)b.x; v[5] = (bf16)b.y; v[6] = (bf16)b.z; v[7] = (bf16)b.w;
    *(bf16x8*)&dst[i] = v;
}

// ---------------------------------------------------------------------------
// bf16 GEMM, C = A @ W^T. 64x128 tile, 4 waves (2x2 of 32x64), BK=64 as two
// BK=32 half-tiles (proven glds layout), 16 MFMA per barrier pair.
// mode 0: split QKV outputs with fused RoPE (+QSCALE on Q).
// mode 1: single fp32 output Co.
// ---------------------------------------------------------------------------
__global__ __launch_bounds__(256)
void gemm64(const bf16* __restrict__ A, const bf16* __restrict__ W, int K,
            bf16* __restrict__ Cq, bf16* __restrict__ Ck, bf16* __restrict__ Cv,
            float* __restrict__ Co, const int* __restrict__ pos, int mode, int N)
{
    __shared__ bf16 As0[64 * 32], As1[64 * 32];
    __shared__ bf16 Bs0[128 * 32], Bs1[128 * 32];

    const int tid  = threadIdx.x;
    const int wave = tid >> 6;
    const int lane = tid & 63;
    const int lr   = lane & 15;
    const int quad = lane >> 4;
    const int m0 = blockIdx.y * 64;
    const int n0 = blockIdx.x * 128;
    const int wm = (wave >> 1) * 32;
    const int wn = (wave & 1) * 64;

    const int srow = (lane >> 2);
    const int scol = (lane & 3) * 8;
    const bf16* Ap  = &A[(size_t)(m0 + wave * 16 + srow) * K + scol];
    const bf16* Wp0 = &W[(size_t)(n0 + wave * 16 + srow) * K + scol];
    const bf16* Wp1 = &W[(size_t)(n0 + 64 + wave * 16 + srow) * K + scol];
    bf16* As0d  = &As0[wave * 512];
    bf16* As1d  = &As1[wave * 512];
    bf16* Bs0d0 = &Bs0[wave * 512];
    bf16* Bs0d1 = &Bs0[(wave + 4) * 512];
    bf16* Bs1d0 = &Bs1[wave * 512];
    bf16* Bs1d1 = &Bs1[(wave + 4) * 512];

    floatx4 acc[2][4];
#pragma unroll
    for (int i = 0; i < 2; i++)
#pragma unroll
        for (int j = 0; j < 4; j++) acc[i][j] = (floatx4)(0.0f);

    for (int k0 = 0; k0 < K; k0 += 64) {
        __syncthreads();
        GLDS16(Ap + k0,       As0d);
        GLDS16(Ap + k0 + 32,  As1d);
        GLDS16(Wp0 + k0,      Bs0d0);
        GLDS16(Wp1 + k0,      Bs0d1);
        GLDS16(Wp0 + k0 + 32, Bs1d0);
        GLDS16(Wp1 + k0 + 32, Bs1d1);
        __syncthreads();

        bf16x8 a0[2], a1[2], b0[4], b1[4];
#pragma unroll
        for (int mi = 0; mi < 2; mi++) {
            a0[mi] = *(const bf16x8*)&As0[(wm + mi * 16 + lr) * 32 + quad * 8];
            a1[mi] = *(const bf16x8*)&As1[(wm + mi * 16 + lr) * 32 + quad * 8];
        }
#pragma unroll
        for (int ni = 0; ni < 4; ni++) {
            b0[ni] = *(const bf16x8*)&Bs0[(wn + ni * 16 + lr) * 32 + quad * 8];
            b1[ni] = *(const bf16x8*)&Bs1[(wn + ni * 16 + lr) * 32 + quad * 8];
        }

#pragma unroll
        for (int mi = 0; mi < 2; mi++)
#pragma unroll
            for (int ni = 0; ni < 4; ni++) {
                acc[mi][ni] = __builtin_amdgcn_mfma_f32_16x16x32_bf16(
                    a0[mi], b0[ni], acc[mi][ni], 0, 0, 0);
                acc[mi][ni] = __builtin_amdgcn_mfma_f32_16x16x32_bf16(
                    a1[mi], b1[ni], acc[mi][ni], 0, 0, 0);
            }
    }

    if (mode == 0) {
        bf16* out; int ld, coff;
        if (n0 < D_MODEL)               { out = Cq; ld = D_MODEL; coff = n0; }
        else if (n0 < D_MODEL + KV_DIM) { out = Ck; ld = KV_DIM;  coff = n0 - D_MODEL; }
        else                            { out = Cv; ld = KV_DIM;  coff = n0 - D_MODEL - KV_DIM; }
        const bool rope = (n0 < D_MODEL + KV_DIM);
        const float sc  = (n0 < D_MODEL) ? QSCALE : 1.0f;
        float inv[4];
        float sgn = (lr & 1) ? 1.0f : -1.0f;
        if (rope) {
#pragma unroll
            for (int ni = 0; ni < 4; ni++) {
                int ip = (ni * 16 + lr) >> 1;
                inv[ni] = exp2f(-(float)ip * FREQ_C);
            }
        }
#pragma unroll
        for (int mi = 0; mi < 2; mi++) {
#pragma unroll
            for (int r = 0; r < 4; r++) {
                int row = m0 + wm + mi * 16 + quad * 4 + r;
                float p = rope ? (float)pos[row & (SEQ_T - 1)] : 0.0f;
#pragma unroll
                for (int ni = 0; ni < 4; ni++) {
                    float v = acc[mi][ni][r];
                    if (rope) {
                        float vp = __shfl_xor(v, 1);
                        float ang = p * inv[ni];
                        float ss, cc;
                        __sincosf(ang, &ss, &cc);
                        v = v * cc + vp * ss * sgn;
                    }
                    out[(size_t)row * ld + coff + wn + ni * 16 + lr] = (bf16)(v * sc);
                }
            }
        }
    } else {
#pragma unroll
        for (int mi = 0; mi < 2; mi++)
#pragma unroll
            for (int ni = 0; ni < 4; ni++)
#pragma unroll
                for (int r = 0; r < 4; r++) {
                    int row = m0 + wm + mi * 16 + quad * 4 + r;
                    int col = n0 + wn + ni * 16 + lr;
                    Co[(size_t)row * N + col] = acc[mi][ni][r];
                }
    }
}

// ---------------------------------------------------------------------------
// V transpose: Vw[b*2048+t][g*64+d] -> Vt[((b*4+g)*64+d)*2048 + t]
// ---------------------------------------------------------------------------
__global__ __launch_bounds__(256)
void transpose_v(const bf16* __restrict__ Vw, bf16* __restrict__ Vt)
{
    __shared__ bf16 Ts[64 * 72];
    const int tid = threadIdx.x;
    const int bg = blockIdx.x >> 5;
    const int tt = blockIdx.x & 31;
    const int b = bg >> 2, g = bg & 3;
    const int t0 = tt * 64;

#pragma unroll
    for (int i = 0; i < 2; i++) {
        int c = tid + i * 256;
        int trow = c >> 3, col8 = (c & 7) * 8;
        *(bf16x8*)&Ts[trow * 72 + col8] =
            *(const bf16x8*)&Vw[(size_t)(b * SEQ_T + t0 + trow) * KV_DIM + g * 64 + col8];
    }
    __syncthreads();
#pragma unroll
    for (int i = 0; i < 2; i++) {
        int c = tid + i * 256;
        int drow = c >> 3, tcol8 = (c & 7) * 8;
        bf16x8 v;
#pragma unroll
        for (int j = 0; j < 8; j++) v[j] = Ts[(tcol8 + j) * 72 + drow];
        *(bf16x8*)&Vt[((size_t)(bg * 64 + drow)) * SEQ_T + t0 + tcol8] = v;
    }
}

// ---------------------------------------------------------------------------
// GQA-fused MFMA flash attention. Block = (b, group, 32-query tile); wave w
// owns head 4g+w. K/Vt tiles staged ONCE per block (shared by 4 heads).
// Q frags loaded global->registers (Q pre-scaled, RoPE'd, exp2 domain).
// No-max softmax (scores bounded); l via MFMA ones-column; P wave-private.
// LDS 39.2 KB.
// ---------------------------------------------------------------------------
__global__ __launch_bounds__(256)
void attn_mfma(const bf16* __restrict__ Q, const bf16* __restrict__ K,
               const bf16* __restrict__ Vt_g, bf16* __restrict__ AO)
{
    const int ST = 72;
    __shared__ bf16 Ks[64 * ST];        // 9.2 KB
    __shared__ bf16 Vt[80 * ST];        // 11.5 KB; row 64 = ones
    __shared__ bf16 Ps[4 * 32 * ST];    // 18.4 KB; wave-private P

    const int tid  = threadIdx.x;
    const int wave = tid >> 6;
    const int lane = tid & 63;
    const int lr   = lane & 15;
    const int quad = lane >> 4;
    const int bg = blockIdx.y;          // b*4+g
    const int b = bg >> 2, g = bg & 3;
    const int h = g * 4 + wave;
    const int q0 = blockIdx.x * 32;

    // Q fragments straight from global (A-frag layout: row=lr, k-contig)
    bf16x8 qf[2][2];
#pragma unroll
    for (int mi = 0; mi < 2; mi++)
#pragma unroll
        for (int ks = 0; ks < 2; ks++)
            qf[mi][ks] = *(const bf16x8*)
                &Q[((size_t)(b * SEQ_T + q0 + mi * 16 + lr)) * D_MODEL
                   + h * 64 + ks * 32 + quad * 8];

    // ones row 64, zero rows 65..79
    for (int i = tid; i < 15 * ST; i += 256) Vt[65 * ST + i] = (bf16)0.0f;
    if (tid < ST) Vt[64 * ST + tid] = (bf16)(tid < 64 ? 1.0f : 0.0f);

    bf16* Pw = &Ps[wave * 32 * ST];

    floatx4 o[2][5];
#pragma unroll
    for (int mi = 0; mi < 2; mi++)
#pragma unroll
        for (int nt = 0; nt < 5; nt++) o[mi][nt] = (floatx4)(0.0f);

    const int t0   = (q0 >= WINDOW) ? ((q0 - WINDOW) & ~63) : 0;
    const int last = q0 & ~63;

    for (int j0 = t0; j0 <= last; j0 += 64) {
        const bool mC = (j0 == last);                   // causal boundary
        const bool mW = (q0 >= WINDOW) && (j0 == t0);   // window boundary
        __syncthreads();   // prev-iter readers done (also covers ones-row init)
        // stage K tile and Vt tile cooperatively
#pragma unroll
        for (int i = 0; i < 2; i++) {
            int c = tid + i * 256;
            int row = c >> 3, col8 = (c & 7) * 8;
            *(bf16x8*)&Ks[row * ST + col8] =
                *(const bf16x8*)&K[((size_t)(b * SEQ_T + j0 + row)) * KV_DIM + g * 64 + col8];
            *(bf16x8*)&Vt[row * ST + col8] =
                *(const bf16x8*)&Vt_g[((size_t)(bg * 64 + row)) * SEQ_T + j0 + col8];
        }
        __syncthreads();

        // S = Q K^T : 2 m-tiles x 4 n-tiles
        floatx4 s[2][4];
#pragma unroll
        for (int mi = 0; mi < 2; mi++)
#pragma unroll
            for (int nt = 0; nt < 4; nt++) s[mi][nt] = (floatx4)(0.0f);
#pragma unroll
        for (int ks = 0; ks < 2; ks++) {
#pragma unroll
            for (int nt = 0; nt < 4; nt++) {
                bf16x8 kf = *(const bf16x8*)&Ks[(nt * 16 + lr) * ST + ks * 32 + quad * 8];
                s[0][nt] = __builtin_amdgcn_mfma_f32_16x16x32_bf16(qf[0][ks], kf, s[0][nt], 0, 0, 0);
                s[1][nt] = __builtin_amdgcn_mfma_f32_16x16x32_bf16(qf[1][ks], kf, s[1][nt], 0, 0, 0);
            }
        }

        if (mC) {
#pragma unroll
            for (int mi = 0; mi < 2; mi++)
#pragma unroll
                for (int nt = 0; nt < 4; nt++) {
                    int key = j0 + nt * 16 + lr;
#pragma unroll
                    for (int r = 0; r < 4; r++) {
                        int qi_ = q0 + mi * 16 + quad * 4 + r;
                        s[mi][nt][r] = (key <= qi_) ? s[mi][nt][r] : -1e30f;
                    }
                }
        } else if (mW) {
#pragma unroll
            for (int mi = 0; mi < 2; mi++)
#pragma unroll
                for (int nt = 0; nt < 4; nt++) {
                    int key = j0 + nt * 16 + lr;
#pragma unroll
                    for (int r = 0; r < 4; r++) {
                        int qi_ = q0 + mi * 16 + quad * 4 + r;
                        s[mi][nt][r] = (qi_ - key <= WINDOW) ? s[mi][nt][r] : -1e30f;
                    }
                }
        }

        // P = exp2(S) -> wave-private LDS (C-layout -> A-frag layout)
#pragma unroll
        for (int mi = 0; mi < 2; mi++)
#pragma unroll
            for (int nt = 0; nt < 4; nt++)
#pragma unroll
                for (int r = 0; r < 4; r++)
                    Pw[(mi * 16 + quad * 4 + r) * ST + nt * 16 + lr] =
                        (bf16)exp2f(s[mi][nt][r]);

        // wave-local RAW fence (DS in-order per wave; no cross-wave hazard)
        __asm__ volatile("s_waitcnt lgkmcnt(0)" ::: "memory");

        // O += P V ; 5th n-tile accumulates l via ones row
#pragma unroll
        for (int ks = 0; ks < 2; ks++) {
            bf16x8 pf0 = *(const bf16x8*)&Pw[(0 + lr) * ST + ks * 32 + quad * 8];
            bf16x8 pf1 = *(const bf16x8*)&Pw[(16 + lr) * ST + ks * 32 + quad * 8];
#pragma unroll
            for (int nt = 0; nt < 5; nt++) {
                bf16x8 vf = *(const bf16x8*)&Vt[(nt * 16 + lr) * ST + ks * 32 + quad * 8];
                o[0][nt] = __builtin_amdgcn_mfma_f32_16x16x32_bf16(pf0, vf, o[0][nt], 0, 0, 0);
                o[1][nt] = __builtin_amdgcn_mfma_f32_16x16x32_bf16(pf1, vf, o[1][nt], 0, 0, 0);
            }
        }
    }

    // epilogue: l sits in n-tile 4, col 64 -> lane lr==0 of each quad group
#pragma unroll
    for (int mi = 0; mi < 2; mi++)
#pragma unroll
        for (int r = 0; r < 4; r++) {
            float l = __shfl(o[mi][4][r], lane & 48);
            float invl = 1.0f / l;
            int row = q0 + mi * 16 + quad * 4 + r;
#pragma unroll
            for (int nt = 0; nt < 4; nt++)
                AO[((size_t)(b * SEQ_T + row)) * D_MODEL + h * 64 + nt * 16 + lr] =
                    (bf16)(o[mi][nt][r] * invl);
        }
}

// ---------------------------------------------------------------------------
extern "C" void kernel_launch(void* const* d_in, const int* in_sizes, int n_in,
                              void* d_out, int out_size, void* d_ws, size_t ws_size,
                              hipStream_t stream)
{
    const float* x  = (const float*)d_in[0];
    const float* WQ = (const float*)d_in[1];
    const float* WK = (const float*)d_in[2];
    const float* WV = (const float*)d_in[3];
    const float* WO = (const float*)d_in[4];
    const int*  pos = (const int*)d_in[5];

    // ws: Qw 8MB | Kw 2MB | Vw 2MB | xb/AO 8MB | Wqkv/Vt_g 3MB | WOb 2MB
    char* ws   = (char*)d_ws;
    bf16* Qw   = (bf16*)ws;
    bf16* Kw   = (bf16*)(ws + (size_t) 8 * 1024 * 1024);
    bf16* Vw   = (bf16*)(ws + (size_t)10 * 1024 * 1024);
    bf16* xb   = (bf16*)(ws + (size_t)12 * 1024 * 1024);
    bf16* AO   = xb;                                        // overlay (xb dead)
    bf16* Wqkv = (bf16*)(ws + (size_t)20 * 1024 * 1024);
    bf16* Vt_g = Wqkv;                                      // overlay (Wqkv dead)
    bf16* WOb  = (bf16*)(ws + (size_t)23 * 1024 * 1024);

    const int cx = (M_ROWS * D_MODEL) / 8;
    const int cq = (D_MODEL * D_MODEL) / 8;
    const int ck = (KV_DIM * D_MODEL) / 8;
    const int ctot = cx + cq + 2 * ck + cq;
    convert_all<<<ctot / 256, 256, 0, stream>>>(
        x, xb, cx,
        WQ, Wqkv, cq,
        WK, Wqkv + (size_t)D_MODEL * D_MODEL, ck,
        WV, Wqkv + (size_t)(D_MODEL + KV_DIM) * D_MODEL, ck,
        WO, WOb, cq);

    // fused QKV projection + RoPE(+QSCALE) epilogue
    gemm64<<<dim3(N_QKV / 128, M_ROWS / 64), 256, 0, stream>>>(
        xb, Wqkv, D_MODEL, Qw, Kw, Vw, nullptr, pos, 0, N_QKV);

    transpose_v<<<256, 256, 0, stream>>>(Vw, Vt_g);

    // GQA-fused attention: grid (q-tiles of 32, b*groups)
    attn_mfma<<<dim3(SEQ_T / 32, BATCH * NUM_GROUPS), 256, 0, stream>>>(
        Qw, Kw, Vt_g, AO);

    // output projection -> fp32 d_out
    gemm64<<<dim3(D_MODEL / 128, M_ROWS / 64), 256, 0, stream>>>(
        AO, WOb, D_MODEL, nullptr, nullptr, nullptr, (float*)d_out, pos, 1, D_MODEL);
}

// Round 9
// 151.270 us; speedup vs baseline: 5.4933x; 1.0280x over previous
//
#include <hip/hip_runtime.h>
#include <hip/hip_bf16.h>

typedef __bf16 bf16;
typedef __bf16 bf16x4 __attribute__((ext_vector_type(4)));
typedef __bf16 bf16x8 __attribute__((ext_vector_type(8)));
typedef float  floatx4 __attribute__((ext_vector_type(4)));

#define D_MODEL   1024
#define NUM_HEADS 16
#define NUM_GROUPS 4
#define DK        64
#define SEQ_T     2048
#define BATCH     2
#define M_ROWS    (BATCH*SEQ_T)   // 4096
#define WINDOW    512
#define KV_DIM    (NUM_GROUPS*DK) // 256
#define N_QKV     (D_MODEL + 2*KV_DIM)  // 1536
// Q pre-scale: 1/sqrt(64) * log2(e)  (exp -> exp2 domain)
#define QSCALE    0.1803368801111204f
// log2(10000)/32
#define FREQ_C    0.4152410118609203f

#define GLDS16(g, l)                                                          \
    __builtin_amdgcn_global_load_lds(                                         \
        (const __attribute__((address_space(1))) void*)(g),                   \
        (__attribute__((address_space(3))) void*)(l), 16, 0, 0)

// ---------------------------------------------------------------------------
// Fused convert: 5 fp32 segments (x, WQ, WK, WV, WO) -> bf16 dsts.
// ---------------------------------------------------------------------------
__global__ __launch_bounds__(256)
void convert_all(const float* s0, bf16* d0, int c0,
                 const float* s1, bf16* d1, int c1,
                 const float* s2, bf16* d2, int c2,
                 const float* s3, bf16* d3, int c3,
                 const float* s4, bf16* d4, int c4)
{
    int id = blockIdx.x * 256 + threadIdx.x;
    const float* src; bf16* dst;
    if      (id < c0)         { src = s0; dst = d0; }
    else if ((id -= c0) < c1) { src = s1; dst = d1; }
    else if ((id -= c1) < c2) { src = s2; dst = d2; }
    else if ((id -= c2) < c3) { src = s3; dst = d3; }
    else if ((id -= c3) < c4) { src = s4; dst = d4; }
    else return;
    int i = id * 8;
    const float* s = src + i;
    float4 a = *(const float4*)s;
    float4 b = *(const float4*)(s + 4);
    bf16x8 v;
    v[0] = (bf16)a.x; v[1] = (bf16)a.y; v[2] = (bf16)a.z; v[3] = (bf16)a.w;
    v[4] = (bf16)b.x; v[5] = (bf16)b.y; v[6] = (bf16)b.z; v[7] = (bf16)b.w;
    *(bf16x8*)&dst[i] = v;
}

// ---------------------------------------------------------------------------
// bf16 GEMM, C = A @ W^T. 64x64 tile (high occupancy for small-N latency
// hiding: QKV grid 1536 = 6 blk/CU, O-proj 1024 = 4 blk/CU). 4 waves, each
// 32x32 (2x2 acc), BK=64 as two proven glds half-tiles; 8 MFMA / iter / wave.
// mode 0: Q (rope+QSCALE) / K (rope) / V (transposed store into Vt) split.
// mode 1: single fp32 output Co.
// ---------------------------------------------------------------------------
__global__ __launch_bounds__(256, 6)
void gemm_t64(const bf16* __restrict__ A, const bf16* __restrict__ W, int K,
              bf16* __restrict__ Cq, bf16* __restrict__ Ck, bf16* __restrict__ Vt,
              float* __restrict__ Co, const int* __restrict__ pos, int mode)
{
    __shared__ bf16 As0[64 * 32], As1[64 * 32];   // 4 KB each
    __shared__ bf16 Bs0[64 * 32], Bs1[64 * 32];   // 4 KB each

    const int tid  = threadIdx.x;
    const int wave = tid >> 6;
    const int lane = tid & 63;
    const int lr   = lane & 15;
    const int quad = lane >> 4;
    const int m0 = blockIdx.y * 64;
    const int n0 = blockIdx.x * 64;
    const int wm = (wave >> 1) * 32;
    const int wn = (wave & 1) * 32;

    // staging: wave w deposits rows w*16..w*16+15 of each 64x32 half-tile;
    // lane L -> row L>>2, col (L&3)*8 (proven lane-order glds layout)
    const int srow = (lane >> 2);
    const int scol = (lane & 3) * 8;
    const bf16* Ap = &A[(size_t)(m0 + wave * 16 + srow) * K + scol];
    const bf16* Wp = &W[(size_t)(n0 + wave * 16 + srow) * K + scol];
    bf16* As0d = &As0[wave * 512];
    bf16* As1d = &As1[wave * 512];
    bf16* Bs0d = &Bs0[wave * 512];
    bf16* Bs1d = &Bs1[wave * 512];

    floatx4 acc[2][2];
#pragma unroll
    for (int i = 0; i < 2; i++)
#pragma unroll
        for (int j = 0; j < 2; j++) acc[i][j] = (floatx4)(0.0f);

    for (int k0 = 0; k0 < K; k0 += 64) {
        __syncthreads();
        GLDS16(Ap + k0,      As0d);
        GLDS16(Ap + k0 + 32, As1d);
        GLDS16(Wp + k0,      Bs0d);
        GLDS16(Wp + k0 + 32, Bs1d);
        __syncthreads();

        bf16x8 a0[2], a1[2], b0[2], b1[2];
#pragma unroll
        for (int mi = 0; mi < 2; mi++) {
            a0[mi] = *(const bf16x8*)&As0[(wm + mi * 16 + lr) * 32 + quad * 8];
            a1[mi] = *(const bf16x8*)&As1[(wm + mi * 16 + lr) * 32 + quad * 8];
        }
#pragma unroll
        for (int ni = 0; ni < 2; ni++) {
            b0[ni] = *(const bf16x8*)&Bs0[(wn + ni * 16 + lr) * 32 + quad * 8];
            b1[ni] = *(const bf16x8*)&Bs1[(wn + ni * 16 + lr) * 32 + quad * 8];
        }

#pragma unroll
        for (int mi = 0; mi < 2; mi++)
#pragma unroll
            for (int ni = 0; ni < 2; ni++) {
                acc[mi][ni] = __builtin_amdgcn_mfma_f32_16x16x32_bf16(
                    a0[mi], b0[ni], acc[mi][ni], 0, 0, 0);
                acc[mi][ni] = __builtin_amdgcn_mfma_f32_16x16x32_bf16(
                    a1[mi], b1[ni], acc[mi][ni], 0, 0, 0);
            }
    }

    if (mode == 0) {
        if (n0 >= D_MODEL + KV_DIM) {
            // ---- V: store transposed into Vt[(bg*64+d)*SEQ_T + t] ----
            const int g  = (n0 - (D_MODEL + KV_DIM)) >> 6;   // 0..3
            const int b  = m0 >> 11;
            const int bg = b * 4 + g;
#pragma unroll
            for (int mi = 0; mi < 2; mi++) {
#pragma unroll
                for (int ni = 0; ni < 2; ni++) {
                    int d  = wn + ni * 16 + lr;
                    int t0 = (m0 & (SEQ_T - 1)) + wm + mi * 16 + quad * 4;
                    bf16x4 v;
#pragma unroll
                    for (int r = 0; r < 4; r++) v[r] = (bf16)acc[mi][ni][r];
                    *(bf16x4*)&Vt[((size_t)(bg * 64 + d)) * SEQ_T + t0] = v;
                }
            }
        } else {
            // ---- Q / K: RoPE epilogue ----
            bf16* out; int ld, coff; float sc;
            if (n0 < D_MODEL) { out = Cq; ld = D_MODEL; coff = n0; sc = QSCALE; }
            else              { out = Ck; ld = KV_DIM;  coff = n0 - D_MODEL; sc = 1.0f; }
            float inv[2];
            float sgn = (lr & 1) ? 1.0f : -1.0f;
#pragma unroll
            for (int ni = 0; ni < 2; ni++) {
                int ip = (wn + ni * 16 + lr) >> 1;      // pair index 0..31 within head
                inv[ni] = exp2f(-(float)ip * FREQ_C);
            }
#pragma unroll
            for (int mi = 0; mi < 2; mi++) {
#pragma unroll
                for (int r = 0; r < 4; r++) {
                    int row = m0 + wm + mi * 16 + quad * 4 + r;
                    float p = (float)pos[row & (SEQ_T - 1)];
#pragma unroll
                    for (int ni = 0; ni < 2; ni++) {
                        float v  = acc[mi][ni][r];
                        float vp = __shfl_xor(v, 1);
                        float ang = p * inv[ni];
                        float ss, cc;
                        __sincosf(ang, &ss, &cc);
                        v = v * cc + vp * ss * sgn;     // even: x1 c - x2 s ; odd: x1 s + x2 c
                        out[(size_t)row * ld + coff + wn + ni * 16 + lr] = (bf16)(v * sc);
                    }
                }
            }
        }
    } else {
#pragma unroll
        for (int mi = 0; mi < 2; mi++)
#pragma unroll
            for (int ni = 0; ni < 2; ni++)
#pragma unroll
                for (int r = 0; r < 4; r++) {
                    int row = m0 + wm + mi * 16 + quad * 4 + r;
                    int col = n0 + wn + ni * 16 + lr;
                    Co[(size_t)row * D_MODEL + col] = acc[mi][ni][r];
                }
    }
}

// ---------------------------------------------------------------------------
// GQA-fused MFMA flash attention (unchanged from R8). Block = (b, group,
// 32-query tile); wave w = head 4g+w; K/Vt staged once per block.
// ---------------------------------------------------------------------------
__global__ __launch_bounds__(256)
void attn_mfma(const bf16* __restrict__ Q, const bf16* __restrict__ K,
               const bf16* __restrict__ Vt_g, bf16* __restrict__ AO)
{
    const int ST = 72;
    __shared__ bf16 Ks[64 * ST];
    __shared__ bf16 Vt[80 * ST];        // row 64 = ones
    __shared__ bf16 Ps[4 * 32 * ST];    // wave-private P

    const int tid  = threadIdx.x;
    const int wave = tid >> 6;
    const int lane = tid & 63;
    const int lr   = lane & 15;
    const int quad = lane >> 4;
    const int bg = blockIdx.y;
    const int b = bg >> 2, g = bg & 3;
    const int h = g * 4 + wave;
    const int q0 = blockIdx.x * 32;

    bf16x8 qf[2][2];
#pragma unroll
    for (int mi = 0; mi < 2; mi++)
#pragma unroll
        for (int ks = 0; ks < 2; ks++)
            qf[mi][ks] = *(const bf16x8*)
                &Q[((size_t)(b * SEQ_T + q0 + mi * 16 + lr)) * D_MODEL
                   + h * 64 + ks * 32 + quad * 8];

    for (int i = tid; i < 15 * ST; i += 256) Vt[65 * ST + i] = (bf16)0.0f;
    if (tid < ST) Vt[64 * ST + tid] = (bf16)(tid < 64 ? 1.0f : 0.0f);

    bf16* Pw = &Ps[wave * 32 * ST];

    floatx4 o[2][5];
#pragma unroll
    for (int mi = 0; mi < 2; mi++)
#pragma unroll
        for (int nt = 0; nt < 5; nt++) o[mi][nt] = (floatx4)(0.0f);

    const int t0   = (q0 >= WINDOW) ? ((q0 - WINDOW) & ~63) : 0;
    const int last = q0 & ~63;

    for (int j0 = t0; j0 <= last; j0 += 64) {
        const bool mC = (j0 == last);
        const bool mW = (q0 >= WINDOW) && (j0 == t0);
        __syncthreads();
#pragma unroll
        for (int i = 0; i < 2; i++) {
            int c = tid + i * 256;
            int row = c >> 3, col8 = (c & 7) * 8;
            *(bf16x8*)&Ks[row * ST + col8] =
                *(const bf16x8*)&K[((size_t)(b * SEQ_T + j0 + row)) * KV_DIM + g * 64 + col8];
            *(bf16x8*)&Vt[row * ST + col8] =
                *(const bf16x8*)&Vt_g[((size_t)(bg * 64 + row)) * SEQ_T + j0 + col8];
        }
        __syncthreads();

        floatx4 s[2][4];
#pragma unroll
        for (int mi = 0; mi < 2; mi++)
#pragma unroll
            for (int nt = 0; nt < 4; nt++) s[mi][nt] = (floatx4)(0.0f);
#pragma unroll
        for (int ks = 0; ks < 2; ks++) {
#pragma unroll
            for (int nt = 0; nt < 4; nt++) {
                bf16x8 kf = *(const bf16x8*)&Ks[(nt * 16 + lr) * ST + ks * 32 + quad * 8];
                s[0][nt] = __builtin_amdgcn_mfma_f32_16x16x32_bf16(qf[0][ks], kf, s[0][nt], 0, 0, 0);
                s[1][nt] = __builtin_amdgcn_mfma_f32_16x16x32_bf16(qf[1][ks], kf, s[1][nt], 0, 0, 0);
            }
        }

        if (mC) {
#pragma unroll
            for (int mi = 0; mi < 2; mi++)
#pragma unroll
                for (int nt = 0; nt < 4; nt++) {
                    int key = j0 + nt * 16 + lr;
#pragma unroll
                    for (int r = 0; r < 4; r++) {
                        int qi_ = q0 + mi * 16 + quad * 4 + r;
                        s[mi][nt][r] = (key <= qi_) ? s[mi][nt][r] : -1e30f;
                    }
                }
        } else if (mW) {
#pragma unroll
            for (int mi = 0; mi < 2; mi++)
#pragma unroll
                for (int nt = 0; nt < 4; nt++) {
                    int key = j0 + nt * 16 + lr;
#pragma unroll
                    for (int r = 0; r < 4; r++) {
                        int qi_ = q0 + mi * 16 + quad * 4 + r;
                        s[mi][nt][r] = (qi_ - key <= WINDOW) ? s[mi][nt][r] : -1e30f;
                    }
                }
        }

#pragma unroll
        for (int mi = 0; mi < 2; mi++)
#pragma unroll
            for (int nt = 0; nt < 4; nt++)
#pragma unroll
                for (int r = 0; r < 4; r++)
                    Pw[(mi * 16 + quad * 4 + r) * ST + nt * 16 + lr] =
                        (bf16)exp2f(s[mi][nt][r]);

        __asm__ volatile("s_waitcnt lgkmcnt(0)" ::: "memory");

#pragma unroll
        for (int ks = 0; ks < 2; ks++) {
            bf16x8 pf0 = *(const bf16x8*)&Pw[(0 + lr) * ST + ks * 32 + quad * 8];
            bf16x8 pf1 = *(const bf16x8*)&Pw[(16 + lr) * ST + ks * 32 + quad * 8];
#pragma unroll
            for (int nt = 0; nt < 5; nt++) {
                bf16x8 vf = *(const bf16x8*)&Vt[(nt * 16 + lr) * ST + ks * 32 + quad * 8];
                o[0][nt] = __builtin_amdgcn_mfma_f32_16x16x32_bf16(pf0, vf, o[0][nt], 0, 0, 0);
                o[1][nt] = __builtin_amdgcn_mfma_f32_16x16x32_bf16(pf1, vf, o[1][nt], 0, 0, 0);
            }
        }
    }

#pragma unroll
    for (int mi = 0; mi < 2; mi++)
#pragma unroll
        for (int r = 0; r < 4; r++) {
            float l = __shfl(o[mi][4][r], lane & 48);
            float invl = 1.0f / l;
            int row = q0 + mi * 16 + quad * 4 + r;
#pragma unroll
            for (int nt = 0; nt < 4; nt++)
                AO[((size_t)(b * SEQ_T + row)) * D_MODEL + h * 64 + nt * 16 + lr] =
                    (bf16)(o[mi][nt][r] * invl);
        }
}

// ---------------------------------------------------------------------------
extern "C" void kernel_launch(void* const* d_in, const int* in_sizes, int n_in,
                              void* d_out, int out_size, void* d_ws, size_t ws_size,
                              hipStream_t stream)
{
    const float* x  = (const float*)d_in[0];
    const float* WQ = (const float*)d_in[1];
    const float* WK = (const float*)d_in[2];
    const float* WV = (const float*)d_in[3];
    const float* WO = (const float*)d_in[4];
    const int*  pos = (const int*)d_in[5];

    // ws: Qw 8MB | Kw 2MB | Vt_g 2MB | xb/AO 8MB | Wqkv 3MB | WOb 2MB
    char* ws   = (char*)d_ws;
    bf16* Qw   = (bf16*)ws;
    bf16* Kw   = (bf16*)(ws + (size_t) 8 * 1024 * 1024);
    bf16* Vt_g = (bf16*)(ws + (size_t)10 * 1024 * 1024);
    bf16* xb   = (bf16*)(ws + (size_t)12 * 1024 * 1024);
    bf16* AO   = xb;                                        // overlay (xb dead)
    bf16* Wqkv = (bf16*)(ws + (size_t)20 * 1024 * 1024);
    bf16* WOb  = (bf16*)(ws + (size_t)23 * 1024 * 1024);

    const int cx = (M_ROWS * D_MODEL) / 8;
    const int cq = (D_MODEL * D_MODEL) / 8;
    const int ck = (KV_DIM * D_MODEL) / 8;
    const int ctot = cx + cq + 2 * ck + cq;
    convert_all<<<ctot / 256, 256, 0, stream>>>(
        x, xb, cx,
        WQ, Wqkv, cq,
        WK, Wqkv + (size_t)D_MODEL * D_MODEL, ck,
        WV, Wqkv + (size_t)(D_MODEL + KV_DIM) * D_MODEL, ck,
        WO, WOb, cq);

    // fused QKV projection + RoPE epilogue + V-transpose epilogue
    gemm_t64<<<dim3(N_QKV / 64, M_ROWS / 64), 256, 0, stream>>>(
        xb, Wqkv, D_MODEL, Qw, Kw, Vt_g, nullptr, pos, 0);

    // GQA-fused attention
    attn_mfma<<<dim3(SEQ_T / 32, BATCH * NUM_GROUPS), 256, 0, stream>>>(
        Qw, Kw, Vt_g, AO);

    // output projection -> fp32 d_out
    gemm_t64<<<dim3(D_MODEL / 64, M_ROWS / 64), 256, 0, stream>>>(
        AO, WOb, D_MODEL, nullptr, nullptr, nullptr, (float*)d_out, pos, 1);
}